// Round 1
// baseline (803.983 us; speedup 1.0000x reference)
//
#include <hip/hip_runtime.h>
#include <cstdint>
#include <cstddef>

typedef __bf16 bf16;
typedef bf16 bf16x8 __attribute__((ext_vector_type(8)));
typedef float f32x4 __attribute__((ext_vector_type(4)));

// ---------------------------------------------------------------- helpers
__device__ __forceinline__ void async_cp16(const void* g, void* l) {
    // global -> LDS direct copy, 16B per lane. LDS dest semantics:
    // wave-uniform base (taken from lane 0) + lane*16.
    __builtin_amdgcn_global_load_lds(
        (const __attribute__((address_space(1))) unsigned int*)(unsigned long long)g,
        (__attribute__((address_space(3))) unsigned int*)(unsigned int)(unsigned long long)l,
        16, 0, 0);
}

// ---------------------------------------------------------------- transpose + cast fp32[R][C] -> bf16[C][R]
__global__ __launch_bounds__(256) void transpose_cast(const float* __restrict__ in,
                                                      bf16* __restrict__ out, int R, int C) {
    __shared__ float tile[32][33];
    int bz = blockIdx.z;
    in  += (size_t)bz * R * C;
    out += (size_t)bz * R * C;
    int c0 = blockIdx.x * 32, r0 = blockIdx.y * 32;
    int tx = threadIdx.x & 31, ty = threadIdx.x >> 5;   // 32 x 8
#pragma unroll
    for (int i = 0; i < 4; ++i)
        tile[ty + i * 8][tx] = in[(size_t)(r0 + ty + i * 8) * C + c0 + tx];
    __syncthreads();
#pragma unroll
    for (int i = 0; i < 4; ++i)
        out[(size_t)(c0 + ty + i * 8) * R + r0 + tx] = (bf16)tile[tx][ty + i * 8];
}

// ---------------------------------------------------------------- rmsnorm (fp32 -> bf16), H=768
__global__ __launch_bounds__(256) void rmsnorm_cast(const float* __restrict__ x,
                                                    const float* __restrict__ w,
                                                    bf16* __restrict__ out) {
    int row = blockIdx.x, tid = threadIdx.x;
    const float* xr = x + (size_t)row * 768;
    float v0 = xr[tid], v1 = xr[tid + 256], v2 = xr[tid + 512];
    float s = v0 * v0 + v1 * v1 + v2 * v2;
#pragma unroll
    for (int off = 32; off; off >>= 1) s += __shfl_xor(s, off, 64);
    __shared__ float red[4];
    if ((tid & 63) == 0) red[tid >> 6] = s;
    __syncthreads();
    float tot = red[0] + red[1] + red[2] + red[3];
    float rs = rsqrtf(tot * (1.f / 768.f) + 1e-6f);
    bf16* o = out + (size_t)row * 768;
    o[tid]       = (bf16)(v0 * rs * w[tid]);
    o[tid + 256] = (bf16)(v1 * rs * w[tid + 256]);
    o[tid + 512] = (bf16)(v2 * rs * w[tid + 512]);
}

// ---------------------------------------------------------------- RoPE + layout transform
// qkv bf16 [t][2304] -> q,k bf16 [bh][s][64] (rotated), v -> vt bf16 [bh][d][s]
__global__ __launch_bounds__(256) void rope_kernel(const bf16* __restrict__ qkv,
                                                   bf16* __restrict__ qb,
                                                   bf16* __restrict__ kb,
                                                   bf16* __restrict__ vtb) {
    __shared__ float vs[64][65];
    const int tid = threadIdx.x;
    const int s0 = blockIdx.x * 64, bh = blockIdx.y;
    const int b = bh / 12, h = bh - b * 12;
#pragma unroll
    for (int i = 0; i < 16; ++i) {
        int idx = i * 256 + tid;
        int sl = idx >> 6, d = idx & 63;
        int sg = s0 + sl;
        size_t base = ((size_t)b * 2048 + sg) * 2304;
        float qv = (float)qkv[base + h * 64 + d];
        float kv = (float)qkv[base + 768 + h * 64 + d];
        float vv = (float)qkv[base + 1536 + h * 64 + d];
        float qp = (float)qkv[base + h * 64 + (d ^ 32)];
        float kp = (float)qkv[base + 768 + h * 64 + (d ^ 32)];
        int jj = d & 31;
        float invf = __expf(-(float)jj * (9.210340371976184f / 32.f)); // 10000^(-j/32)
        float ang = (float)sg * invf;
        float cv = cosf(ang), sv = sinf(ang);
        float rq = (d < 32) ? -qp : qp;
        float rk = (d < 32) ? -kp : kp;
        qb[((size_t)bh * 2048 + sg) * 64 + d] = (bf16)(qv * cv + rq * sv);
        kb[((size_t)bh * 2048 + sg) * 64 + d] = (bf16)(kv * cv + rk * sv);
        vs[sl][d] = vv;
    }
    __syncthreads();
#pragma unroll
    for (int i = 0; i < 16; ++i) {
        int idx = i * 256 + tid;
        int d = idx >> 6, sl = idx & 63;
        vtb[(size_t)bh * 64 * 2048 + (size_t)d * 2048 + s0 + sl] = (bf16)vs[sl][d];
    }
}

// ---------------------------------------------------------------- flash attention (causal)
// grid (16 qtiles, 24 bh), 256 thr. Q-tile 128, KV-tile 64, Dh 64.
__global__ __launch_bounds__(256) void attn_kernel(const bf16* __restrict__ qb,
                                                   const bf16* __restrict__ kb,
                                                   const bf16* __restrict__ vtb,
                                                   bf16* __restrict__ ob) {
    __shared__ __align__(16) bf16 Qs[128 * 64];
    __shared__ __align__(16) bf16 Ks[64 * 64];
    __shared__ __align__(16) bf16 Vts[64 * 64];
    __shared__ __align__(16) bf16 Ps[4 * 32 * 64];

    const int tid = threadIdx.x, lane = tid & 63, w = tid >> 6;
    const int quad = lane >> 4, l16 = lane & 15;
    const int qt = blockIdx.x, bh = blockIdx.y;
    const int q0 = qt * 128;
    const int b = bh / 12, h = bh - b * 12;

    const bf16* qhead = qb + (size_t)bh * 2048 * 64;
    const bf16* khead = kb + (size_t)bh * 2048 * 64;
    const bf16* vthead = vtb + (size_t)bh * 64 * 2048;

#pragma unroll
    for (int i = 0; i < 4; ++i) {   // stage Q once: 1024 16B chunks
        int c = i * 256 + tid;
        int r = c >> 3, koff = (c & 7) * 8;
        async_cp16(qhead + (size_t)(q0 + r) * 64 + koff,
                   (char*)Qs + (size_t)(i * 256 + w * 64) * 16);
    }

    f32x4 o_acc[2][4] = {};
    float m_st[2][4], l_st[2][4];
#pragma unroll
    for (int mi = 0; mi < 2; ++mi)
#pragma unroll
        for (int r = 0; r < 4; ++r) { m_st[mi][r] = -1e30f; l_st[mi][r] = 0.f; }

    const int jmax = 2 * qt + 1;
    for (int j = 0; j <= jmax; ++j) {
        int kv0 = j * 64;
        __syncthreads();
#pragma unroll
        for (int i = 0; i < 2; ++i) {   // stage K tile [s][d]
            int c = i * 256 + tid;
            int r = c >> 3, koff = (c & 7) * 8;
            async_cp16(khead + (size_t)(kv0 + r) * 64 + koff,
                       (char*)Ks + (size_t)(i * 256 + w * 64) * 16);
        }
#pragma unroll
        for (int i = 0; i < 2; ++i) {   // stage Vt tile [d][s]
            int c = i * 256 + tid;
            int r = c >> 3, koff = (c & 7) * 8;
            async_cp16(vthead + (size_t)r * 2048 + kv0 + koff,
                       (char*)Vts + (size_t)(i * 256 + w * 64) * 16);
        }
        __syncthreads();

        // S = Q K^T : wave w owns q-rows [w*32, w*32+32)
        f32x4 sacc[2][4] = {};
#pragma unroll
        for (int kk = 0; kk < 2; ++kk) {
            bf16x8 aq[2], bk[4];
#pragma unroll
            for (int mi = 0; mi < 2; ++mi)
                aq[mi] = *(const bf16x8*)(Qs + (w * 32 + mi * 16 + l16) * 64 + kk * 32 + quad * 8);
#pragma unroll
            for (int ni = 0; ni < 4; ++ni)
                bk[ni] = *(const bf16x8*)(Ks + (ni * 16 + l16) * 64 + kk * 32 + quad * 8);
#pragma unroll
            for (int mi = 0; mi < 2; ++mi)
#pragma unroll
                for (int ni = 0; ni < 4; ++ni)
                    sacc[mi][ni] = __builtin_amdgcn_mfma_f32_16x16x32_bf16(aq[mi], bk[ni], sacc[mi][ni], 0, 0, 0);
        }
        // scale + causal mask (only diagonal-adjacent tiles need it)
        bool needMask = (j >= 2 * qt);
#pragma unroll
        for (int mi = 0; mi < 2; ++mi)
#pragma unroll
            for (int ni = 0; ni < 4; ++ni)
#pragma unroll
                for (int r = 0; r < 4; ++r) {
                    float sv = sacc[mi][ni][r] * 0.125f;
                    if (needMask) {
                        int rowg = q0 + w * 32 + mi * 16 + quad * 4 + r;
                        int colg = kv0 + ni * 16 + l16;
                        if (colg > rowg) sv = -1e30f;
                    }
                    sacc[mi][ni][r] = sv;
                }
        // online softmax (rows live in one quad: reduce over 16 lanes)
        float alpha[2][4];
#pragma unroll
        for (int mi = 0; mi < 2; ++mi)
#pragma unroll
            for (int r = 0; r < 4; ++r) {
                float mx = sacc[mi][0][r];
#pragma unroll
                for (int ni = 1; ni < 4; ++ni) mx = fmaxf(mx, sacc[mi][ni][r]);
#pragma unroll
                for (int off = 1; off < 16; off <<= 1) mx = fmaxf(mx, __shfl_xor(mx, off, 64));
                float mnew = fmaxf(m_st[mi][r], mx);
                alpha[mi][r] = __expf(m_st[mi][r] - mnew);
                m_st[mi][r] = mnew;
                float rsum = 0.f;
#pragma unroll
                for (int ni = 0; ni < 4; ++ni) {
                    float pv = __expf(sacc[mi][ni][r] - mnew);
                    sacc[mi][ni][r] = pv;
                    rsum += pv;
                }
#pragma unroll
                for (int off = 1; off < 16; off <<= 1) rsum += __shfl_xor(rsum, off, 64);
                l_st[mi][r] = l_st[mi][r] * alpha[mi][r] + rsum;
            }
#pragma unroll
        for (int mi = 0; mi < 2; ++mi)
#pragma unroll
            for (int ni = 0; ni < 4; ++ni)
#pragma unroll
                for (int r = 0; r < 4; ++r) o_acc[mi][ni][r] *= alpha[mi][r];

        // P: C-layout -> LDS -> A-layout (per-wave private region)
        bf16* pw_ = Ps + w * 32 * 64;
#pragma unroll
        for (int mi = 0; mi < 2; ++mi)
#pragma unroll
            for (int ni = 0; ni < 4; ++ni)
#pragma unroll
                for (int r = 0; r < 4; ++r)
                    pw_[(mi * 16 + quad * 4 + r) * 64 + ni * 16 + l16] = (bf16)sacc[mi][ni][r];

        // O += P V
#pragma unroll
        for (int kk = 0; kk < 2; ++kk) {
            bf16x8 ap[2], bv[4];
#pragma unroll
            for (int mi = 0; mi < 2; ++mi)
                ap[mi] = *(const bf16x8*)(pw_ + (mi * 16 + l16) * 64 + kk * 32 + quad * 8);
#pragma unroll
            for (int ni = 0; ni < 4; ++ni)
                bv[ni] = *(const bf16x8*)(Vts + (ni * 16 + l16) * 64 + kk * 32 + quad * 8);
#pragma unroll
            for (int mi = 0; mi < 2; ++mi)
#pragma unroll
                for (int ni = 0; ni < 4; ++ni)
                    o_acc[mi][ni] = __builtin_amdgcn_mfma_f32_16x16x32_bf16(ap[mi], bv[ni], o_acc[mi][ni], 0, 0, 0);
        }
    }

#pragma unroll
    for (int mi = 0; mi < 2; ++mi)
#pragma unroll
        for (int ni = 0; ni < 4; ++ni)
#pragma unroll
            for (int r = 0; r < 4; ++r) {
                int rowg = q0 + w * 32 + mi * 16 + quad * 4 + r;
                float v = o_acc[mi][ni][r] / l_st[mi][r];
                size_t t = (size_t)b * 2048 + rowg;
                ob[t * 768 + h * 64 + ni * 16 + l16] = (bf16)v;
            }
}

// ---------------------------------------------------------------- fused rmsnorm2 + router
__global__ __launch_bounds__(256) void rms_router(const float* __restrict__ x1,
                                                  const float* __restrict__ w,
                                                  const float* __restrict__ rw,
                                                  bf16* __restrict__ hn,
                                                  int* __restrict__ topi,
                                                  float* __restrict__ topw,
                                                  int* __restrict__ ctrl) {
    __shared__ float hnf[768];
    __shared__ float part[256];
    __shared__ float lg[8];
    __shared__ float probs[8];
    __shared__ float red[4];
    int row = blockIdx.x, tid = threadIdx.x;
    const float* xr = x1 + (size_t)row * 768;
    float v0 = xr[tid], v1 = xr[tid + 256], v2 = xr[tid + 512];
    float s = v0 * v0 + v1 * v1 + v2 * v2;
#pragma unroll
    for (int off = 32; off; off >>= 1) s += __shfl_xor(s, off, 64);
    if ((tid & 63) == 0) red[tid >> 6] = s;
    __syncthreads();
    float tot = red[0] + red[1] + red[2] + red[3];
    float rs = rsqrtf(tot * (1.f / 768.f) + 1e-6f);
    float h0 = v0 * rs * w[tid], h1v = v1 * rs * w[tid + 256], h2v = v2 * rs * w[tid + 512];
    hnf[tid] = h0; hnf[tid + 256] = h1v; hnf[tid + 512] = h2v;
    bf16* o = hn + (size_t)row * 768;
    o[tid] = (bf16)h0; o[tid + 256] = (bf16)h1v; o[tid + 512] = (bf16)h2v;
    __syncthreads();
    // logits: 8 experts x 32 segments of 24
    int e = tid & 7, seg = tid >> 3;
    float p = 0.f;
#pragma unroll
    for (int j = 0; j < 24; ++j) { int k = seg * 24 + j; p += hnf[k] * rw[k * 8 + e]; }
    part[tid] = p;
    __syncthreads();
    if (tid < 8) { float a = 0.f; for (int sgi = 0; sgi < 32; ++sgi) a += part[sgi * 8 + tid]; lg[tid] = a; }
    __syncthreads();
    if (tid == 0) {
        float mx = lg[0];
        for (int i = 1; i < 8; ++i) mx = fmaxf(mx, lg[i]);
        float ssum = 0.f, ex[8];
        for (int i = 0; i < 8; ++i) { ex[i] = __expf(lg[i] - mx); ssum += ex[i]; }
        float inv = 1.f / ssum;
        for (int i = 0; i < 8; ++i) probs[i] = ex[i] * inv;
        int e0 = 0; float p0 = probs[0];
        for (int i = 1; i < 8; ++i) if (probs[i] > p0) { p0 = probs[i]; e0 = i; }
        int e1 = -1; float p1 = -1.f;
        for (int i = 0; i < 8; ++i) if (i != e0 && probs[i] > p1) { p1 = probs[i]; e1 = i; }
        float wsum = p0 + p1;
        topi[row * 2] = e0; topi[row * 2 + 1] = e1;
        topw[row * 2] = p0 / wsum; topw[row * 2 + 1] = p1 / wsum;
        atomicAdd(&ctrl[e0], 1); atomicAdd(&ctrl[e1], 1);
    }
    __syncthreads();
    if (tid < 8) atomicAdd((float*)&ctrl[8 + tid], probs[tid]);
}

// ---------------------------------------------------------------- tile descriptors + aux loss
__global__ void build_tiles(int* ctrl, int4* tiles, float* auxOut) {
    if (threadIdx.x == 0) {
        int off = 0, nt = 0;
        for (int e = 0; e < 8; ++e) {
            int ne = ctrl[e];
            ctrl[32 + e] = off;                       // poff
            int ntl = (ne + 127) >> 7;
            for (int i = 0; i < ntl; ++i) { tiles[nt] = make_int4(e, off + i * 128, off + ne, 0); ++nt; }
            off += ntl << 7;
        }
        ctrl[24] = nt;
        const float* psum = (const float*)&ctrl[8];
        float aux = 0.f;
        for (int e = 0; e < 8; ++e)
            aux += ((float)ctrl[e] * (1.f / 8192.f)) * (psum[e] * (1.f / 4096.f));
        auxOut[0] = 8.f * aux;
    }
}

// ---------------------------------------------------------------- token placement (grouping)
__global__ __launch_bounds__(256) void place_tokens(const int* __restrict__ topi,
                                                    const float* __restrict__ topw,
                                                    int* ctrl, int* __restrict__ perm,
                                                    float* __restrict__ pw) {
    int t = blockIdx.x * 256 + threadIdx.x;
#pragma unroll
    for (int k = 0; k < 2; ++k) {
        int e = topi[t * 2 + k];
        int pos = atomicAdd(&ctrl[16 + e], 1);
        int g = ctrl[32 + e] + pos;
        perm[g] = t;
        pw[g] = topw[t * 2 + k];
    }
}

// ---------------------------------------------------------------- NT GEMM: C[M,N] = A[M,K] @ Bt[N,K]^T
// MODE 0: out bf16 (qkv)   MODE 1: out fp32 + residual (wo)
// MODE 2: gathered rows (perm) + silu -> bf16 (moe h1)
// MODE 3: direct rows + weighted atomicAdd scatter (moe out)
template <int MODE>
__global__ __launch_bounds__(256) void gemm_nt(const bf16* __restrict__ A,
                                               const bf16* __restrict__ Bt,
                                               int M, int N, int K,
                                               const float* __restrict__ xres,
                                               float* __restrict__ outF,
                                               bf16* __restrict__ outB,
                                               const int4* __restrict__ tiles,
                                               const int* __restrict__ ctrl,
                                               const int* __restrict__ perm,
                                               const float* __restrict__ pw) {
    __shared__ __align__(16) bf16 As[128 * 32];
    __shared__ __align__(16) bf16 Bs[128 * 32];
    __shared__ int sPerm[128];
    __shared__ float sPw[128];

    const int tid = threadIdx.x, lane = tid & 63, w = tid >> 6;
    const int wr = w >> 1, wc = w & 1, quad = lane >> 4, l16 = lane & 15;

    int m0 = 0, n0 = blockIdx.x * 128, row0 = 0, rowend = 0;
    if (MODE <= 1) {
        m0 = blockIdx.y * 128;
    } else {
        if ((int)blockIdx.y >= ctrl[24]) return;
        int4 td = tiles[blockIdx.y];
        row0 = td.y; rowend = td.z;
        Bt += (size_t)td.x * N * K;
        if (tid < 128) {
            int g = row0 + tid;
            int gs = (g < rowend) ? g : row0;   // clamp padded rows to a valid one
            sPerm[tid] = perm[gs];
            sPw[tid] = pw[gs];
        }
    }

    f32x4 acc[4][4] = {};

    for (int kt = 0; kt < K; kt += 32) {
        __syncthreads();
#pragma unroll
        for (int i = 0; i < 2; ++i) {           // stage A tile 128x32
            int c = i * 256 + tid;
            int r = c >> 2, koff = (c & 3) * 8;
            const bf16* gp;
            if (MODE == 2)      gp = A + (size_t)sPerm[r] * K + kt + koff;
            else if (MODE == 3) gp = A + (size_t)(row0 + r) * K + kt + koff;
            else                gp = A + (size_t)(m0 + r) * K + kt + koff;
            async_cp16(gp, (char*)As + (size_t)(i * 256 + w * 64) * 16);
        }
#pragma unroll
        for (int i = 0; i < 2; ++i) {           // stage B tile 128x32
            int c = i * 256 + tid;
            int r = c >> 2, koff = (c & 3) * 8;
            async_cp16(Bt + (size_t)(n0 + r) * K + kt + koff,
                       (char*)Bs + (size_t)(i * 256 + w * 64) * 16);
        }
        __syncthreads();

        bf16x8 af[4], bfr[4];
#pragma unroll
        for (int mi = 0; mi < 4; ++mi)
            af[mi] = *(const bf16x8*)(As + (wr * 64 + mi * 16 + l16) * 32 + quad * 8);
#pragma unroll
        for (int ni = 0; ni < 4; ++ni)
            bfr[ni] = *(const bf16x8*)(Bs + (wc * 64 + ni * 16 + l16) * 32 + quad * 8);
#pragma unroll
        for (int mi = 0; mi < 4; ++mi)
#pragma unroll
            for (int ni = 0; ni < 4; ++ni)
                acc[mi][ni] = __builtin_amdgcn_mfma_f32_16x16x32_bf16(af[mi], bfr[ni], acc[mi][ni], 0, 0, 0);
    }

#pragma unroll
    for (int mi = 0; mi < 4; ++mi)
#pragma unroll
        for (int ni = 0; ni < 4; ++ni)
#pragma unroll
            for (int r = 0; r < 4; ++r) {
                int lrow = wr * 64 + mi * 16 + quad * 4 + r;
                int col = n0 + wc * 64 + ni * 16 + l16;
                float v = acc[mi][ni][r];
                if (MODE == 0) {
                    outB[(size_t)(m0 + lrow) * N + col] = (bf16)v;
                } else if (MODE == 1) {
                    size_t idx = (size_t)(m0 + lrow) * N + col;
                    outF[idx] = v + xres[idx];
                } else if (MODE == 2) {
                    float sv = v / (1.f + __expf(-v));   // silu
                    outB[(size_t)(row0 + lrow) * N + col] = (bf16)sv;
                } else {
                    if (row0 + lrow < rowend)
                        atomicAdd(&outF[(size_t)sPerm[lrow] * N + col], v * sPw[lrow]);
                }
            }
}

__global__ void zero_ctrl(int* ctrl) { if (threadIdx.x < 64) ctrl[threadIdx.x] = 0; }

// ---------------------------------------------------------------- launch
extern "C" void kernel_launch(void* const* d_in, const int* in_sizes, int n_in,
                              void* d_out, int out_size, void* d_ws, size_t ws_size,
                              hipStream_t stream) {
    const float* x    = (const float*)d_in[0];
    const float* anw  = (const float*)d_in[1];
    const float* wqkv = (const float*)d_in[2];
    const float* wo   = (const float*)d_in[3];
    const float* fnw  = (const float*)d_in[4];
    const float* rw   = (const float*)d_in[5];
    const float* w1   = (const float*)d_in[6];
    const float* w2   = (const float*)d_in[7];
    float* out = (float*)d_out;

    char* ws = (char*)d_ws;
    size_t off = 0;
    auto alloc = [&](size_t bytes) -> char* {
        char* p = ws + off;
        off = (off + bytes + 255) & ~(size_t)255;
        return p;
    };
    bf16* wqkvT = (bf16*)alloc(2304ull * 768 * 2);
    bf16* woT   = (bf16*)alloc(768ull * 768 * 2);
    bf16* w1T   = (bf16*)alloc(8ull * 3072 * 768 * 2);
    bf16* w2T   = (bf16*)alloc(8ull * 768 * 3072 * 2);
    bf16* hbuf  = (bf16*)alloc(4096ull * 768 * 2);
    bf16* qkvb  = (bf16*)alloc(4096ull * 2304 * 2);
    bf16* qb    = (bf16*)alloc(24ull * 2048 * 64 * 2);
    bf16* kb    = (bf16*)alloc(24ull * 2048 * 64 * 2);
    bf16* vtb   = (bf16*)alloc(24ull * 64 * 2048 * 2);
    bf16* obuf  = (bf16*)alloc(4096ull * 768 * 2);
    bf16* hn    = (bf16*)alloc(4096ull * 768 * 2);
    int*  topi  = (int*)alloc(4096ull * 2 * 4);
    float* topw = (float*)alloc(4096ull * 2 * 4);
    int*  ctrl  = (int*)alloc(64 * 4);
    int4* tiles = (int4*)alloc(80 * 16);
    int*  perm  = (int*)alloc(9216 * 4);
    float* pwv  = (float*)alloc(9216 * 4);
    bf16* h1    = (bf16*)alloc(9216ull * 3072 * 2);
    (void)ws_size; (void)in_sizes; (void)n_in;

    zero_ctrl<<<1, 64, 0, stream>>>(ctrl);
    // weight transpose+casts to bf16 [N][K]
    transpose_cast<<<dim3(72, 24, 1), 256, 0, stream>>>(wqkv, wqkvT, 768, 2304);
    transpose_cast<<<dim3(24, 24, 1), 256, 0, stream>>>(wo, woT, 768, 768);
    transpose_cast<<<dim3(96, 24, 8), 256, 0, stream>>>(w1, w1T, 768, 3072);
    transpose_cast<<<dim3(24, 96, 8), 256, 0, stream>>>(w2, w2T, 3072, 768);
    // attention block
    rmsnorm_cast<<<4096, 256, 0, stream>>>(x, anw, hbuf);
    gemm_nt<0><<<dim3(18, 32), 256, 0, stream>>>(hbuf, wqkvT, 4096, 2304, 768,
                                                 nullptr, nullptr, qkvb, nullptr, nullptr, nullptr, nullptr);
    rope_kernel<<<dim3(32, 24), 256, 0, stream>>>(qkvb, qb, kb, vtb);
    attn_kernel<<<dim3(16, 24), 256, 0, stream>>>(qb, kb, vtb, obuf);
    gemm_nt<1><<<dim3(6, 32), 256, 0, stream>>>(obuf, woT, 4096, 768, 768,
                                                x, out, nullptr, nullptr, nullptr, nullptr, nullptr);
    // MoE block
    rms_router<<<4096, 256, 0, stream>>>(out, fnw, rw, hn, topi, topw, ctrl);
    build_tiles<<<1, 64, 0, stream>>>(ctrl, tiles, out + (out_size - 1));
    place_tokens<<<16, 256, 0, stream>>>(topi, topw, ctrl, perm, pwv);
    gemm_nt<2><<<dim3(24, 72), 256, 0, stream>>>(hn, w1T, 0, 3072, 768,
                                                 nullptr, nullptr, h1, tiles, ctrl, perm, pwv);
    gemm_nt<3><<<dim3(6, 72), 256, 0, stream>>>(h1, w2T, 0, 768, 3072,
                                                nullptr, out, nullptr, tiles, ctrl, perm, pwv);
}

// Round 2
// 770.345 us; speedup vs baseline: 1.0437x; 1.0437x over previous
//
#include <hip/hip_runtime.h>
#include <cstdint>
#include <cstddef>

typedef __bf16 bf16;
typedef bf16 bf16x8 __attribute__((ext_vector_type(8)));
typedef float f32x4 __attribute__((ext_vector_type(4)));

// ---------------------------------------------------------------- helpers
__device__ __forceinline__ void async_cp16(const void* g, void* l) {
    // global -> LDS direct copy, 16B per lane. LDS dest semantics:
    // wave-uniform base (taken from lane 0) + lane*16.
    __builtin_amdgcn_global_load_lds(
        (const __attribute__((address_space(1))) unsigned int*)(unsigned long long)g,
        (__attribute__((address_space(3))) unsigned int*)(unsigned int)(unsigned long long)l,
        16, 0, 0);
}

// ---------------------------------------------------------------- transpose + cast fp32[R][C] -> bf16[C][R]
__global__ __launch_bounds__(256) void transpose_cast(const float* __restrict__ in,
                                                      bf16* __restrict__ out, int R, int C) {
    __shared__ float tile[32][33];
    int bz = blockIdx.z;
    in  += (size_t)bz * R * C;
    out += (size_t)bz * R * C;
    int c0 = blockIdx.x * 32, r0 = blockIdx.y * 32;
    int tx = threadIdx.x & 31, ty = threadIdx.x >> 5;   // 32 x 8
#pragma unroll
    for (int i = 0; i < 4; ++i)
        tile[ty + i * 8][tx] = in[(size_t)(r0 + ty + i * 8) * C + c0 + tx];
    __syncthreads();
#pragma unroll
    for (int i = 0; i < 4; ++i)
        out[(size_t)(c0 + ty + i * 8) * R + r0 + tx] = (bf16)tile[tx][ty + i * 8];
}

// ---------------------------------------------------------------- rmsnorm (fp32 -> bf16), H=768
__global__ __launch_bounds__(256) void rmsnorm_cast(const float* __restrict__ x,
                                                    const float* __restrict__ w,
                                                    bf16* __restrict__ out) {
    int row = blockIdx.x, tid = threadIdx.x;
    const float* xr = x + (size_t)row * 768;
    float v0 = xr[tid], v1 = xr[tid + 256], v2 = xr[tid + 512];
    float s = v0 * v0 + v1 * v1 + v2 * v2;
#pragma unroll
    for (int off = 32; off; off >>= 1) s += __shfl_xor(s, off, 64);
    __shared__ float red[4];
    if ((tid & 63) == 0) red[tid >> 6] = s;
    __syncthreads();
    float tot = red[0] + red[1] + red[2] + red[3];
    float rs = rsqrtf(tot * (1.f / 768.f) + 1e-6f);
    bf16* o = out + (size_t)row * 768;
    o[tid]       = (bf16)(v0 * rs * w[tid]);
    o[tid + 256] = (bf16)(v1 * rs * w[tid + 256]);
    o[tid + 512] = (bf16)(v2 * rs * w[tid + 512]);
}

// ---------------------------------------------------------------- RoPE + layout transform
// qkv bf16 [t][2304] -> q,k bf16 [bh][s][64] (rotated), v -> vt bf16 [bh][d][s]
__global__ __launch_bounds__(256) void rope_kernel(const bf16* __restrict__ qkv,
                                                   bf16* __restrict__ qb,
                                                   bf16* __restrict__ kb,
                                                   bf16* __restrict__ vtb) {
    __shared__ float vs[64][65];
    const int tid = threadIdx.x;
    const int s0 = blockIdx.x * 64, bh = blockIdx.y;
    const int b = bh / 12, h = bh - b * 12;
#pragma unroll
    for (int i = 0; i < 16; ++i) {
        int idx = i * 256 + tid;
        int sl = idx >> 6, d = idx & 63;
        int sg = s0 + sl;
        size_t base = ((size_t)b * 2048 + sg) * 2304;
        float qv = (float)qkv[base + h * 64 + d];
        float kv = (float)qkv[base + 768 + h * 64 + d];
        float vv = (float)qkv[base + 1536 + h * 64 + d];
        float qp = (float)qkv[base + h * 64 + (d ^ 32)];
        float kp = (float)qkv[base + 768 + h * 64 + (d ^ 32)];
        int jj = d & 31;
        float invf = __expf(-(float)jj * (9.210340371976184f / 32.f)); // 10000^(-j/32)
        float ang = (float)sg * invf;
        float cv = cosf(ang), sv = sinf(ang);
        float rq = (d < 32) ? -qp : qp;
        float rk = (d < 32) ? -kp : kp;
        qb[((size_t)bh * 2048 + sg) * 64 + d] = (bf16)(qv * cv + rq * sv);
        kb[((size_t)bh * 2048 + sg) * 64 + d] = (bf16)(kv * cv + rk * sv);
        vs[sl][d] = vv;
    }
    __syncthreads();
#pragma unroll
    for (int i = 0; i < 16; ++i) {
        int idx = i * 256 + tid;
        int d = idx >> 6, sl = idx & 63;
        vtb[(size_t)bh * 64 * 2048 + (size_t)d * 2048 + s0 + sl] = (bf16)vs[sl][d];
    }
}

// ---------------------------------------------------------------- flash attention (causal)
// grid (32 qtiles reversed, 24 bh), 256 thr. Q-tile 64, KV-tile 64, Dh 64.
// LDS layouts: Q/K/Vt as 2 K-panels [2][64][32] (bank-spread rows, async-stageable);
// P per-wave [16][64] with 16B-chunk XOR swizzle (chunk ^= row&7).
__global__ __launch_bounds__(256, 5) void attn_kernel(const bf16* __restrict__ qb,
                                                      const bf16* __restrict__ kb,
                                                      const bf16* __restrict__ vtb,
                                                      bf16* __restrict__ ob) {
    __shared__ __align__(16) bf16 Qs[2][64][32];
    __shared__ __align__(16) bf16 Ks[2][64][32];
    __shared__ __align__(16) bf16 Vts[2][64][32];
    __shared__ __align__(16) bf16 Ps[4][1024];

    const int tid = threadIdx.x, lane = tid & 63, w = tid >> 6;
    const int quad = lane >> 4, l16 = lane & 15;
    const int qt = 31 - (int)blockIdx.x, bh = blockIdx.y;   // largest-first scheduling
    const int q0 = qt * 64;
    const int b = bh / 12, h = bh - b * 12;

    const bf16* qhead = qb + (size_t)bh * 2048 * 64;
    const bf16* khead = kb + (size_t)bh * 2048 * 64;
    const bf16* vthead = vtb + (size_t)bh * 64 * 2048;

    // stage Q once: 8KB. Lane's LDS dest is linear offset o; gather the global
    // element that belongs at o in the [2][64][32] panel layout.
#pragma unroll
    for (int i = 0; i < 2; ++i) {
        int o = (i * 256 + tid) * 16;
        int kk = o >> 12, row = (o >> 6) & 63, el = (o & 63) >> 1;
        async_cp16(qhead + (size_t)(q0 + row) * 64 + kk * 32 + el,
                   (char*)Qs + (size_t)(i * 256 + w * 64) * 16);
    }

    f32x4 o_acc[4] = {};
    float m_st[4], l_st[4];
#pragma unroll
    for (int r = 0; r < 4; ++r) { m_st[r] = -1e30f; l_st[r] = 0.f; }

    const float sscale = 0.18033688f;   // 0.125 * log2(e)  (softmax in exp2 domain)

    for (int j = 0; j <= qt; ++j) {
        int kv0 = j * 64;
        __syncthreads();
#pragma unroll
        for (int i = 0; i < 2; ++i) {   // K tile -> panels
            int o = (i * 256 + tid) * 16;
            int kk = o >> 12, row = (o >> 6) & 63, el = (o & 63) >> 1;
            async_cp16(khead + (size_t)(kv0 + row) * 64 + kk * 32 + el,
                       (char*)Ks + (size_t)(i * 256 + w * 64) * 16);
        }
#pragma unroll
        for (int i = 0; i < 2; ++i) {   // Vt tile -> panels (row = d, inner = s)
            int o = (i * 256 + tid) * 16;
            int kk = o >> 12, row = (o >> 6) & 63, el = (o & 63) >> 1;
            async_cp16(vthead + (size_t)row * 2048 + kv0 + kk * 32 + el,
                       (char*)Vts + (size_t)(i * 256 + w * 64) * 16);
        }
        __syncthreads();

        // S = Q K^T : wave w owns q-rows [w*16, w*16+16)
        f32x4 sacc[4] = {};
#pragma unroll
        for (int kk = 0; kk < 2; ++kk) {
            bf16x8 aq = *(const bf16x8*)&Qs[kk][w * 16 + l16][quad * 8];
            bf16x8 bk[4];
#pragma unroll
            for (int ni = 0; ni < 4; ++ni)
                bk[ni] = *(const bf16x8*)&Ks[kk][ni * 16 + l16][quad * 8];
#pragma unroll
            for (int ni = 0; ni < 4; ++ni)
                sacc[ni] = __builtin_amdgcn_mfma_f32_16x16x32_bf16(aq, bk[ni], sacc[ni], 0, 0, 0);
        }

        // scale + causal mask (only the diagonal tile needs the compare)
        bool needMask = (j == qt);
#pragma unroll
        for (int ni = 0; ni < 4; ++ni)
#pragma unroll
            for (int r = 0; r < 4; ++r) {
                float sv = sacc[ni][r] * sscale;
                if (needMask) {
                    int rowg = q0 + w * 16 + quad * 4 + r;
                    int colg = kv0 + ni * 16 + l16;
                    if (colg > rowg) sv = -1e30f;
                }
                sacc[ni][r] = sv;
            }

        // online softmax (row lives across 16 lanes of a quad: 4 shfl steps)
        float alpha[4];
#pragma unroll
        for (int r = 0; r < 4; ++r) {
            float mx = sacc[0][r];
#pragma unroll
            for (int ni = 1; ni < 4; ++ni) mx = fmaxf(mx, sacc[ni][r]);
#pragma unroll
            for (int off = 1; off < 16; off <<= 1) mx = fmaxf(mx, __shfl_xor(mx, off, 64));
            float mnew = fmaxf(m_st[r], mx);
            alpha[r] = exp2f(m_st[r] - mnew);
            m_st[r] = mnew;
            float rsum = 0.f;
#pragma unroll
            for (int ni = 0; ni < 4; ++ni) {
                float pv = exp2f(sacc[ni][r] - mnew);
                sacc[ni][r] = pv;
                rsum += pv;
            }
#pragma unroll
            for (int off = 1; off < 16; off <<= 1) rsum += __shfl_xor(rsum, off, 64);
            l_st[r] = l_st[r] * alpha[r] + rsum;
        }
#pragma unroll
        for (int ni = 0; ni < 4; ++ni)
#pragma unroll
            for (int r = 0; r < 4; ++r) o_acc[ni][r] *= alpha[r];

        // P: C-layout -> LDS (XOR-swizzled 16B chunks) -> A-layout
        bf16* pb = Ps[w];
#pragma unroll
        for (int ni = 0; ni < 4; ++ni)
#pragma unroll
            for (int r = 0; r < 4; ++r) {
                int prow = quad * 4 + r, pcol = ni * 16 + l16;
                int ch = (pcol >> 3) ^ (prow & 7);
                pb[prow * 64 + ch * 8 + (pcol & 7)] = (bf16)sacc[ni][r];
            }

        // O += P V
#pragma unroll
        for (int kk = 0; kk < 2; ++kk) {
            int ch = (kk * 4 + quad) ^ (l16 & 7);
            bf16x8 ap = *(const bf16x8*)&pb[l16 * 64 + ch * 8];
            bf16x8 bv[4];
#pragma unroll
            for (int ni = 0; ni < 4; ++ni)
                bv[ni] = *(const bf16x8*)&Vts[kk][ni * 16 + l16][quad * 8];
#pragma unroll
            for (int ni = 0; ni < 4; ++ni)
                o_acc[ni] = __builtin_amdgcn_mfma_f32_16x16x32_bf16(ap, bv[ni], o_acc[ni], 0, 0, 0);
        }
    }

    float inv_l[4];
#pragma unroll
    for (int r = 0; r < 4; ++r) inv_l[r] = 1.f / l_st[r];
#pragma unroll
    for (int ni = 0; ni < 4; ++ni)
#pragma unroll
        for (int r = 0; r < 4; ++r) {
            int rowg = q0 + w * 16 + quad * 4 + r;
            size_t t = (size_t)b * 2048 + rowg;
            ob[t * 768 + h * 64 + ni * 16 + l16] = (bf16)(o_acc[ni][r] * inv_l[r]);
        }
}

// ---------------------------------------------------------------- fused rmsnorm2 + router
__global__ __launch_bounds__(256) void rms_router(const float* __restrict__ x1,
                                                  const float* __restrict__ w,
                                                  const float* __restrict__ rw,
                                                  bf16* __restrict__ hn,
                                                  int* __restrict__ topi,
                                                  float* __restrict__ topw,
                                                  int* __restrict__ ctrl) {
    __shared__ float hnf[768];
    __shared__ float part[256];
    __shared__ float lg[8];
    __shared__ float probs[8];
    __shared__ float red[4];
    int row = blockIdx.x, tid = threadIdx.x;
    const float* xr = x1 + (size_t)row * 768;
    float v0 = xr[tid], v1 = xr[tid + 256], v2 = xr[tid + 512];
    float s = v0 * v0 + v1 * v1 + v2 * v2;
#pragma unroll
    for (int off = 32; off; off >>= 1) s += __shfl_xor(s, off, 64);
    if ((tid & 63) == 0) red[tid >> 6] = s;
    __syncthreads();
    float tot = red[0] + red[1] + red[2] + red[3];
    float rs = rsqrtf(tot * (1.f / 768.f) + 1e-6f);
    float h0 = v0 * rs * w[tid], h1v = v1 * rs * w[tid + 256], h2v = v2 * rs * w[tid + 512];
    hnf[tid] = h0; hnf[tid + 256] = h1v; hnf[tid + 512] = h2v;
    bf16* o = hn + (size_t)row * 768;
    o[tid] = (bf16)h0; o[tid + 256] = (bf16)h1v; o[tid + 512] = (bf16)h2v;
    __syncthreads();
    // logits: 8 experts x 32 segments of 24
    int e = tid & 7, seg = tid >> 3;
    float p = 0.f;
#pragma unroll
    for (int j = 0; j < 24; ++j) { int k = seg * 24 + j; p += hnf[k] * rw[k * 8 + e]; }
    part[tid] = p;
    __syncthreads();
    if (tid < 8) { float a = 0.f; for (int sgi = 0; sgi < 32; ++sgi) a += part[sgi * 8 + tid]; lg[tid] = a; }
    __syncthreads();
    if (tid == 0) {
        float mx = lg[0];
        for (int i = 1; i < 8; ++i) mx = fmaxf(mx, lg[i]);
        float ssum = 0.f, ex[8];
        for (int i = 0; i < 8; ++i) { ex[i] = __expf(lg[i] - mx); ssum += ex[i]; }
        float inv = 1.f / ssum;
        for (int i = 0; i < 8; ++i) probs[i] = ex[i] * inv;
        int e0 = 0; float p0 = probs[0];
        for (int i = 1; i < 8; ++i) if (probs[i] > p0) { p0 = probs[i]; e0 = i; }
        int e1 = -1; float p1 = -1.f;
        for (int i = 0; i < 8; ++i) if (i != e0 && probs[i] > p1) { p1 = probs[i]; e1 = i; }
        float wsum = p0 + p1;
        topi[row * 2] = e0; topi[row * 2 + 1] = e1;
        topw[row * 2] = p0 / wsum; topw[row * 2 + 1] = p1 / wsum;
        atomicAdd(&ctrl[e0], 1); atomicAdd(&ctrl[e1], 1);
    }
    __syncthreads();
    if (tid < 8) atomicAdd((float*)&ctrl[8 + tid], probs[tid]);
}

// ---------------------------------------------------------------- tile descriptors + aux loss
__global__ void build_tiles(int* ctrl, int4* tiles, float* auxOut) {
    if (threadIdx.x == 0) {
        int off = 0, nt = 0;
        for (int e = 0; e < 8; ++e) {
            int ne = ctrl[e];
            ctrl[32 + e] = off;                       // poff
            int ntl = (ne + 127) >> 7;
            for (int i = 0; i < ntl; ++i) { tiles[nt] = make_int4(e, off + i * 128, off + ne, 0); ++nt; }
            off += ntl << 7;
        }
        ctrl[24] = nt;
        const float* psum = (const float*)&ctrl[8];
        float aux = 0.f;
        for (int e = 0; e < 8; ++e)
            aux += ((float)ctrl[e] * (1.f / 8192.f)) * (psum[e] * (1.f / 4096.f));
        auxOut[0] = 8.f * aux;
    }
}

// ---------------------------------------------------------------- token placement (grouping)
__global__ __launch_bounds__(256) void place_tokens(const int* __restrict__ topi,
                                                    const float* __restrict__ topw,
                                                    int* ctrl, int* __restrict__ perm,
                                                    float* __restrict__ pw) {
    int t = blockIdx.x * 256 + threadIdx.x;
#pragma unroll
    for (int k = 0; k < 2; ++k) {
        int e = topi[t * 2 + k];
        int pos = atomicAdd(&ctrl[16 + e], 1);
        int g = ctrl[32 + e] + pos;
        perm[g] = t;
        pw[g] = topw[t * 2 + k];
    }
}

// ---------------------------------------------------------------- NT GEMM: C[M,N] = A[M,K] @ Bt[N,K]^T
// MODE 0: out bf16 (qkv)   MODE 1: out fp32 + residual (wo)
// MODE 2: gathered rows (perm) + silu -> bf16 (moe h1)
// MODE 3: direct rows + weighted atomicAdd scatter (moe out)
template <int MODE>
__global__ __launch_bounds__(256) void gemm_nt(const bf16* __restrict__ A,
                                               const bf16* __restrict__ Bt,
                                               int M, int N, int K,
                                               const float* __restrict__ xres,
                                               float* __restrict__ outF,
                                               bf16* __restrict__ outB,
                                               const int4* __restrict__ tiles,
                                               const int* __restrict__ ctrl,
                                               const int* __restrict__ perm,
                                               const float* __restrict__ pw) {
    __shared__ __align__(16) bf16 As[128 * 32];
    __shared__ __align__(16) bf16 Bs[128 * 32];
    __shared__ int sPerm[128];
    __shared__ float sPw[128];

    const int tid = threadIdx.x, lane = tid & 63, w = tid >> 6;
    const int wr = w >> 1, wc = w & 1, quad = lane >> 4, l16 = lane & 15;

    int m0 = 0, n0 = blockIdx.x * 128, row0 = 0, rowend = 0;
    if (MODE <= 1) {
        m0 = blockIdx.y * 128;
    } else {
        if ((int)blockIdx.y >= ctrl[24]) return;
        int4 td = tiles[blockIdx.y];
        row0 = td.y; rowend = td.z;
        Bt += (size_t)td.x * N * K;
        if (tid < 128) {
            int g = row0 + tid;
            int gs = (g < rowend) ? g : row0;   // clamp padded rows to a valid one
            sPerm[tid] = perm[gs];
            sPw[tid] = pw[gs];
        }
    }

    f32x4 acc[4][4] = {};

    for (int kt = 0; kt < K; kt += 32) {
        __syncthreads();
#pragma unroll
        for (int i = 0; i < 2; ++i) {           // stage A tile 128x32
            int c = i * 256 + tid;
            int r = c >> 2, koff = (c & 3) * 8;
            const bf16* gp;
            if (MODE == 2)      gp = A + (size_t)sPerm[r] * K + kt + koff;
            else if (MODE == 3) gp = A + (size_t)(row0 + r) * K + kt + koff;
            else                gp = A + (size_t)(m0 + r) * K + kt + koff;
            async_cp16(gp, (char*)As + (size_t)(i * 256 + w * 64) * 16);
        }
#pragma unroll
        for (int i = 0; i < 2; ++i) {           // stage B tile 128x32
            int c = i * 256 + tid;
            int r = c >> 2, koff = (c & 3) * 8;
            async_cp16(Bt + (size_t)(n0 + r) * K + kt + koff,
                       (char*)Bs + (size_t)(i * 256 + w * 64) * 16);
        }
        __syncthreads();

        bf16x8 af[4], bfr[4];
#pragma unroll
        for (int mi = 0; mi < 4; ++mi)
            af[mi] = *(const bf16x8*)(As + (wr * 64 + mi * 16 + l16) * 32 + quad * 8);
#pragma unroll
        for (int ni = 0; ni < 4; ++ni)
            bfr[ni] = *(const bf16x8*)(Bs + (wc * 64 + ni * 16 + l16) * 32 + quad * 8);
#pragma unroll
        for (int mi = 0; mi < 4; ++mi)
#pragma unroll
            for (int ni = 0; ni < 4; ++ni)
                acc[mi][ni] = __builtin_amdgcn_mfma_f32_16x16x32_bf16(af[mi], bfr[ni], acc[mi][ni], 0, 0, 0);
    }

#pragma unroll
    for (int mi = 0; mi < 4; ++mi)
#pragma unroll
        for (int ni = 0; ni < 4; ++ni)
#pragma unroll
            for (int r = 0; r < 4; ++r) {
                int lrow = wr * 64 + mi * 16 + quad * 4 + r;
                int col = n0 + wc * 64 + ni * 16 + l16;
                float v = acc[mi][ni][r];
                if (MODE == 0) {
                    outB[(size_t)(m0 + lrow) * N + col] = (bf16)v;
                } else if (MODE == 1) {
                    size_t idx = (size_t)(m0 + lrow) * N + col;
                    outF[idx] = v + xres[idx];
                } else if (MODE == 2) {
                    float sv = v / (1.f + __expf(-v));   // silu
                    outB[(size_t)(row0 + lrow) * N + col] = (bf16)sv;
                } else {
                    if (row0 + lrow < rowend)
                        atomicAdd(&outF[(size_t)sPerm[lrow] * N + col], v * sPw[lrow]);
                }
            }
}

__global__ void zero_ctrl(int* ctrl) { if (threadIdx.x < 64) ctrl[threadIdx.x] = 0; }

// ---------------------------------------------------------------- launch
extern "C" void kernel_launch(void* const* d_in, const int* in_sizes, int n_in,
                              void* d_out, int out_size, void* d_ws, size_t ws_size,
                              hipStream_t stream) {
    const float* x    = (const float*)d_in[0];
    const float* anw  = (const float*)d_in[1];
    const float* wqkv = (const float*)d_in[2];
    const float* wo   = (const float*)d_in[3];
    const float* fnw  = (const float*)d_in[4];
    const float* rw   = (const float*)d_in[5];
    const float* w1   = (const float*)d_in[6];
    const float* w2   = (const float*)d_in[7];
    float* out = (float*)d_out;

    char* ws = (char*)d_ws;
    size_t off = 0;
    auto alloc = [&](size_t bytes) -> char* {
        char* p = ws + off;
        off = (off + bytes + 255) & ~(size_t)255;
        return p;
    };
    bf16* wqkvT = (bf16*)alloc(2304ull * 768 * 2);
    bf16* woT   = (bf16*)alloc(768ull * 768 * 2);
    bf16* w1T   = (bf16*)alloc(8ull * 3072 * 768 * 2);
    bf16* w2T   = (bf16*)alloc(8ull * 768 * 3072 * 2);
    bf16* hbuf  = (bf16*)alloc(4096ull * 768 * 2);
    bf16* qkvb  = (bf16*)alloc(4096ull * 2304 * 2);
    bf16* qb    = (bf16*)alloc(24ull * 2048 * 64 * 2);
    bf16* kb    = (bf16*)alloc(24ull * 2048 * 64 * 2);
    bf16* vtb   = (bf16*)alloc(24ull * 64 * 2048 * 2);
    bf16* obuf  = (bf16*)alloc(4096ull * 768 * 2);
    bf16* hn    = (bf16*)alloc(4096ull * 768 * 2);
    int*  topi  = (int*)alloc(4096ull * 2 * 4);
    float* topw = (float*)alloc(4096ull * 2 * 4);
    int*  ctrl  = (int*)alloc(64 * 4);
    int4* tiles = (int4*)alloc(80 * 16);
    int*  perm  = (int*)alloc(9216 * 4);
    float* pwv  = (float*)alloc(9216 * 4);
    bf16* h1    = (bf16*)alloc(9216ull * 3072 * 2);
    (void)ws_size; (void)in_sizes; (void)n_in;

    zero_ctrl<<<1, 64, 0, stream>>>(ctrl);
    // weight transpose+casts to bf16 [N][K]
    transpose_cast<<<dim3(72, 24, 1), 256, 0, stream>>>(wqkv, wqkvT, 768, 2304);
    transpose_cast<<<dim3(24, 24, 1), 256, 0, stream>>>(wo, woT, 768, 768);
    transpose_cast<<<dim3(96, 24, 8), 256, 0, stream>>>(w1, w1T, 768, 3072);
    transpose_cast<<<dim3(24, 96, 8), 256, 0, stream>>>(w2, w2T, 3072, 768);
    // attention block
    rmsnorm_cast<<<4096, 256, 0, stream>>>(x, anw, hbuf);
    gemm_nt<0><<<dim3(18, 32), 256, 0, stream>>>(hbuf, wqkvT, 4096, 2304, 768,
                                                 nullptr, nullptr, qkvb, nullptr, nullptr, nullptr, nullptr);
    rope_kernel<<<dim3(32, 24), 256, 0, stream>>>(qkvb, qb, kb, vtb);
    attn_kernel<<<dim3(32, 24), 256, 0, stream>>>(qb, kb, vtb, obuf);
    gemm_nt<1><<<dim3(6, 32), 256, 0, stream>>>(obuf, woT, 4096, 768, 768,
                                                x, out, nullptr, nullptr, nullptr, nullptr, nullptr);
    // MoE block
    rms_router<<<4096, 256, 0, stream>>>(out, fnw, rw, hn, topi, topw, ctrl);
    build_tiles<<<1, 64, 0, stream>>>(ctrl, tiles, out + (out_size - 1));
    place_tokens<<<16, 256, 0, stream>>>(topi, topw, ctrl, perm, pwv);
    gemm_nt<2><<<dim3(24, 72), 256, 0, stream>>>(hn, w1T, 0, 3072, 768,
                                                 nullptr, nullptr, h1, tiles, ctrl, perm, pwv);
    gemm_nt<3><<<dim3(6, 72), 256, 0, stream>>>(h1, w2T, 0, 768, 3072,
                                                nullptr, out, nullptr, tiles, ctrl, perm, pwv);
}

// Round 3
// 606.061 us; speedup vs baseline: 1.3266x; 1.2711x over previous
//
#include <hip/hip_runtime.h>
#include <cstdint>
#include <cstddef>

typedef __bf16 bf16;
typedef bf16 bf16x8 __attribute__((ext_vector_type(8)));
typedef float f32x4 __attribute__((ext_vector_type(4)));

// ---------------------------------------------------------------- helpers
__device__ __forceinline__ void async_cp16(const void* g, void* l) {
    // global -> LDS direct copy, 16B per lane. LDS dest semantics:
    // wave-uniform base (taken from lane 0) + lane*16.
    __builtin_amdgcn_global_load_lds(
        (const __attribute__((address_space(1))) unsigned int*)(unsigned long long)g,
        (__attribute__((address_space(3))) unsigned int*)(unsigned int)(unsigned long long)l,
        16, 0, 0);
}

// ---------------------------------------------------------------- transpose + cast fp32[R][C] -> bf16[C][R]
__global__ __launch_bounds__(256) void transpose_cast(const float* __restrict__ in,
                                                      bf16* __restrict__ out, int R, int C) {
    __shared__ float tile[32][33];
    int bz = blockIdx.z;
    in  += (size_t)bz * R * C;
    out += (size_t)bz * R * C;
    int c0 = blockIdx.x * 32, r0 = blockIdx.y * 32;
    int tx = threadIdx.x & 31, ty = threadIdx.x >> 5;   // 32 x 8
#pragma unroll
    for (int i = 0; i < 4; ++i)
        tile[ty + i * 8][tx] = in[(size_t)(r0 + ty + i * 8) * C + c0 + tx];
    __syncthreads();
#pragma unroll
    for (int i = 0; i < 4; ++i)
        out[(size_t)(c0 + ty + i * 8) * R + r0 + tx] = (bf16)tile[tx][ty + i * 8];
}

// ---------------------------------------------------------------- rmsnorm (fp32 -> bf16), H=768
__global__ __launch_bounds__(256) void rmsnorm_cast(const float* __restrict__ x,
                                                    const float* __restrict__ w,
                                                    bf16* __restrict__ out) {
    int row = blockIdx.x, tid = threadIdx.x;
    const float* xr = x + (size_t)row * 768;
    float v0 = xr[tid], v1 = xr[tid + 256], v2 = xr[tid + 512];
    float s = v0 * v0 + v1 * v1 + v2 * v2;
#pragma unroll
    for (int off = 32; off; off >>= 1) s += __shfl_xor(s, off, 64);
    __shared__ float red[4];
    if ((tid & 63) == 0) red[tid >> 6] = s;
    __syncthreads();
    float tot = red[0] + red[1] + red[2] + red[3];
    float rs = rsqrtf(tot * (1.f / 768.f) + 1e-6f);
    bf16* o = out + (size_t)row * 768;
    o[tid]       = (bf16)(v0 * rs * w[tid]);
    o[tid + 256] = (bf16)(v1 * rs * w[tid + 256]);
    o[tid + 512] = (bf16)(v2 * rs * w[tid + 512]);
}

// ---------------------------------------------------------------- RoPE + layout transform
// qkv bf16 [t][2304] -> q,k bf16 [bh][s][64] (rotated), v -> vt bf16 [bh][d][s]
__global__ __launch_bounds__(256) void rope_kernel(const bf16* __restrict__ qkv,
                                                   bf16* __restrict__ qb,
                                                   bf16* __restrict__ kb,
                                                   bf16* __restrict__ vtb) {
    __shared__ float vs[64][65];
    const int tid = threadIdx.x;
    const int s0 = blockIdx.x * 64, bh = blockIdx.y;
    const int b = bh / 12, h = bh - b * 12;
#pragma unroll
    for (int i = 0; i < 16; ++i) {
        int idx = i * 256 + tid;
        int sl = idx >> 6, d = idx & 63;
        int sg = s0 + sl;
        size_t base = ((size_t)b * 2048 + sg) * 2304;
        float qv = (float)qkv[base + h * 64 + d];
        float kv = (float)qkv[base + 768 + h * 64 + d];
        float vv = (float)qkv[base + 1536 + h * 64 + d];
        float qp = (float)qkv[base + h * 64 + (d ^ 32)];
        float kp = (float)qkv[base + 768 + h * 64 + (d ^ 32)];
        int jj = d & 31;
        float invf = __expf(-(float)jj * (9.210340371976184f / 32.f)); // 10000^(-j/32)
        float ang = (float)sg * invf;
        float cv = cosf(ang), sv = sinf(ang);
        float rq = (d < 32) ? -qp : qp;
        float rk = (d < 32) ? -kp : kp;
        qb[((size_t)bh * 2048 + sg) * 64 + d] = (bf16)(qv * cv + rq * sv);
        kb[((size_t)bh * 2048 + sg) * 64 + d] = (bf16)(kv * cv + rk * sv);
        vs[sl][d] = vv;
    }
    __syncthreads();
#pragma unroll
    for (int i = 0; i < 16; ++i) {
        int idx = i * 256 + tid;
        int d = idx >> 6, sl = idx & 63;
        vtb[(size_t)bh * 64 * 2048 + (size_t)d * 2048 + s0 + sl] = (bf16)vs[sl][d];
    }
}

// ---------------------------------------------------------------- flash attention (causal)
// grid (32 qtiles reversed, 24 bh), 256 thr. Q-tile 64, KV-tile 64, Dh 64.
__global__ __launch_bounds__(256, 5) void attn_kernel(const bf16* __restrict__ qb,
                                                      const bf16* __restrict__ kb,
                                                      const bf16* __restrict__ vtb,
                                                      bf16* __restrict__ ob) {
    __shared__ __align__(16) bf16 Qs[2][64][32];
    __shared__ __align__(16) bf16 Ks[2][64][32];
    __shared__ __align__(16) bf16 Vts[2][64][32];
    __shared__ __align__(16) bf16 Ps[4][1024];

    const int tid = threadIdx.x, lane = tid & 63, w = tid >> 6;
    const int quad = lane >> 4, l16 = lane & 15;
    const int qt = 31 - (int)blockIdx.x, bh = blockIdx.y;   // largest-first scheduling
    const int q0 = qt * 64;
    const int b = bh / 12, h = bh - b * 12;

    const bf16* qhead = qb + (size_t)bh * 2048 * 64;
    const bf16* khead = kb + (size_t)bh * 2048 * 64;
    const bf16* vthead = vtb + (size_t)bh * 64 * 2048;

#pragma unroll
    for (int i = 0; i < 2; ++i) {
        int o = (i * 256 + tid) * 16;
        int kk = o >> 12, row = (o >> 6) & 63, el = (o & 63) >> 1;
        async_cp16(qhead + (size_t)(q0 + row) * 64 + kk * 32 + el,
                   (char*)Qs + (size_t)(i * 256 + w * 64) * 16);
    }

    f32x4 o_acc[4] = {};
    float m_st[4], l_st[4];
#pragma unroll
    for (int r = 0; r < 4; ++r) { m_st[r] = -1e30f; l_st[r] = 0.f; }

    const float sscale = 0.18033688f;   // 0.125 * log2(e)  (softmax in exp2 domain)

    for (int j = 0; j <= qt; ++j) {
        int kv0 = j * 64;
        __syncthreads();
#pragma unroll
        for (int i = 0; i < 2; ++i) {   // K tile -> panels
            int o = (i * 256 + tid) * 16;
            int kk = o >> 12, row = (o >> 6) & 63, el = (o & 63) >> 1;
            async_cp16(khead + (size_t)(kv0 + row) * 64 + kk * 32 + el,
                       (char*)Ks + (size_t)(i * 256 + w * 64) * 16);
        }
#pragma unroll
        for (int i = 0; i < 2; ++i) {   // Vt tile -> panels (row = d, inner = s)
            int o = (i * 256 + tid) * 16;
            int kk = o >> 12, row = (o >> 6) & 63, el = (o & 63) >> 1;
            async_cp16(vthead + (size_t)row * 2048 + kv0 + kk * 32 + el,
                       (char*)Vts + (size_t)(i * 256 + w * 64) * 16);
        }
        __syncthreads();

        f32x4 sacc[4] = {};
#pragma unroll
        for (int kk = 0; kk < 2; ++kk) {
            bf16x8 aq = *(const bf16x8*)&Qs[kk][w * 16 + l16][quad * 8];
            bf16x8 bk[4];
#pragma unroll
            for (int ni = 0; ni < 4; ++ni)
                bk[ni] = *(const bf16x8*)&Ks[kk][ni * 16 + l16][quad * 8];
#pragma unroll
            for (int ni = 0; ni < 4; ++ni)
                sacc[ni] = __builtin_amdgcn_mfma_f32_16x16x32_bf16(aq, bk[ni], sacc[ni], 0, 0, 0);
        }

        bool needMask = (j == qt);
#pragma unroll
        for (int ni = 0; ni < 4; ++ni)
#pragma unroll
            for (int r = 0; r < 4; ++r) {
                float sv = sacc[ni][r] * sscale;
                if (needMask) {
                    int rowg = q0 + w * 16 + quad * 4 + r;
                    int colg = kv0 + ni * 16 + l16;
                    if (colg > rowg) sv = -1e30f;
                }
                sacc[ni][r] = sv;
            }

        float alpha[4];
#pragma unroll
        for (int r = 0; r < 4; ++r) {
            float mx = sacc[0][r];
#pragma unroll
            for (int ni = 1; ni < 4; ++ni) mx = fmaxf(mx, sacc[ni][r]);
#pragma unroll
            for (int off = 1; off < 16; off <<= 1) mx = fmaxf(mx, __shfl_xor(mx, off, 64));
            float mnew = fmaxf(m_st[r], mx);
            alpha[r] = exp2f(m_st[r] - mnew);
            m_st[r] = mnew;
            float rsum = 0.f;
#pragma unroll
            for (int ni = 0; ni < 4; ++ni) {
                float pv = exp2f(sacc[ni][r] - mnew);
                sacc[ni][r] = pv;
                rsum += pv;
            }
#pragma unroll
            for (int off = 1; off < 16; off <<= 1) rsum += __shfl_xor(rsum, off, 64);
            l_st[r] = l_st[r] * alpha[r] + rsum;
        }
#pragma unroll
        for (int ni = 0; ni < 4; ++ni)
#pragma unroll
            for (int r = 0; r < 4; ++r) o_acc[ni][r] *= alpha[r];

        bf16* pb = Ps[w];
#pragma unroll
        for (int ni = 0; ni < 4; ++ni)
#pragma unroll
            for (int r = 0; r < 4; ++r) {
                int prow = quad * 4 + r, pcol = ni * 16 + l16;
                int ch = (pcol >> 3) ^ (prow & 7);
                pb[prow * 64 + ch * 8 + (pcol & 7)] = (bf16)sacc[ni][r];
            }

#pragma unroll
        for (int kk = 0; kk < 2; ++kk) {
            int ch = (kk * 4 + quad) ^ (l16 & 7);
            bf16x8 ap = *(const bf16x8*)&pb[l16 * 64 + ch * 8];
            bf16x8 bv[4];
#pragma unroll
            for (int ni = 0; ni < 4; ++ni)
                bv[ni] = *(const bf16x8*)&Vts[kk][ni * 16 + l16][quad * 8];
#pragma unroll
            for (int ni = 0; ni < 4; ++ni)
                o_acc[ni] = __builtin_amdgcn_mfma_f32_16x16x32_bf16(ap, bv[ni], o_acc[ni], 0, 0, 0);
        }
    }

    float inv_l[4];
#pragma unroll
    for (int r = 0; r < 4; ++r) inv_l[r] = 1.f / l_st[r];
#pragma unroll
    for (int ni = 0; ni < 4; ++ni)
#pragma unroll
        for (int r = 0; r < 4; ++r) {
            int rowg = q0 + w * 16 + quad * 4 + r;
            size_t t = (size_t)b * 2048 + rowg;
            ob[t * 768 + h * 64 + ni * 16 + l16] = (bf16)(o_acc[ni][r] * inv_l[r]);
        }
}

// ---------------------------------------------------------------- fused rmsnorm2 + router (NO atomics)
__global__ __launch_bounds__(256) void rms_router(const float* __restrict__ x1,
                                                  const float* __restrict__ w,
                                                  const float* __restrict__ rw,
                                                  bf16* __restrict__ hn,
                                                  int* __restrict__ topi,
                                                  float* __restrict__ topw,
                                                  float* __restrict__ probsb) {
    __shared__ float hnf[768];
    __shared__ float part[256];
    __shared__ float lg[8];
    __shared__ float probs[8];
    __shared__ float red[4];
    int row = blockIdx.x, tid = threadIdx.x;
    const float* xr = x1 + (size_t)row * 768;
    float v0 = xr[tid], v1 = xr[tid + 256], v2 = xr[tid + 512];
    float s = v0 * v0 + v1 * v1 + v2 * v2;
#pragma unroll
    for (int off = 32; off; off >>= 1) s += __shfl_xor(s, off, 64);
    if ((tid & 63) == 0) red[tid >> 6] = s;
    __syncthreads();
    float tot = red[0] + red[1] + red[2] + red[3];
    float rs = rsqrtf(tot * (1.f / 768.f) + 1e-6f);
    float h0 = v0 * rs * w[tid], h1v = v1 * rs * w[tid + 256], h2v = v2 * rs * w[tid + 512];
    hnf[tid] = h0; hnf[tid + 256] = h1v; hnf[tid + 512] = h2v;
    bf16* o = hn + (size_t)row * 768;
    o[tid] = (bf16)h0; o[tid + 256] = (bf16)h1v; o[tid + 512] = (bf16)h2v;
    __syncthreads();
    // logits: 8 experts x 32 segments of 24
    int e = tid & 7, seg = tid >> 3;
    float p = 0.f;
#pragma unroll
    for (int j = 0; j < 24; ++j) { int k = seg * 24 + j; p += hnf[k] * rw[k * 8 + e]; }
    part[tid] = p;
    __syncthreads();
    if (tid < 8) { float a = 0.f; for (int sgi = 0; sgi < 32; ++sgi) a += part[sgi * 8 + tid]; lg[tid] = a; }
    __syncthreads();
    if (tid == 0) {
        float mx = lg[0];
        for (int i = 1; i < 8; ++i) mx = fmaxf(mx, lg[i]);
        float ssum = 0.f, ex[8];
        for (int i = 0; i < 8; ++i) { ex[i] = __expf(lg[i] - mx); ssum += ex[i]; }
        float inv = 1.f / ssum;
        for (int i = 0; i < 8; ++i) probs[i] = ex[i] * inv;
        int e0 = 0; float p0 = probs[0];
        for (int i = 1; i < 8; ++i) if (probs[i] > p0) { p0 = probs[i]; e0 = i; }
        int e1 = -1; float p1 = -1.f;
        for (int i = 0; i < 8; ++i) if (i != e0 && probs[i] > p1) { p1 = probs[i]; e1 = i; }
        float wsum = p0 + p1;
        topi[row * 2] = e0; topi[row * 2 + 1] = e1;
        topw[row * 2] = p0 / wsum; topw[row * 2 + 1] = p1 / wsum;
    }
    __syncthreads();
    if (tid < 8) probsb[(size_t)row * 8 + tid] = probs[tid];
}

// ---------------------------------------------------------------- router stats + tiles + aux (single block)
__global__ __launch_bounds__(256) void router_stats(const float* __restrict__ probsb,
                                                    const int* __restrict__ topi,
                                                    int* ctrl, int4* tiles, float* auxOut) {
    __shared__ float pws[4][8];
    __shared__ int cws[4][8];
    int tid = threadIdx.x;
    float s[8] = {};
    int cnt[8] = {};
    for (int t = tid; t < 4096; t += 256) {
        const float4* p = (const float4*)(probsb + (size_t)t * 8);
        float4 a = p[0], b = p[1];
        s[0] += a.x; s[1] += a.y; s[2] += a.z; s[3] += a.w;
        s[4] += b.x; s[5] += b.y; s[6] += b.z; s[7] += b.w;
        int e0 = topi[2 * t], e1 = topi[2 * t + 1];
#pragma unroll
        for (int e = 0; e < 8; ++e) cnt[e] += (e == e0) + (e == e1);
    }
#pragma unroll
    for (int e = 0; e < 8; ++e)
#pragma unroll
        for (int off = 32; off; off >>= 1) {
            s[e] += __shfl_xor(s[e], off, 64);
            cnt[e] += __shfl_xor(cnt[e], off, 64);
        }
    if ((tid & 63) == 0) {
#pragma unroll
        for (int e = 0; e < 8; ++e) { pws[tid >> 6][e] = s[e]; cws[tid >> 6][e] = cnt[e]; }
    }
    __syncthreads();
    if (tid == 0) {
        int off = 0, nt = 0;
        float aux = 0.f;
        for (int e = 0; e < 8; ++e) {
            int ne = cws[0][e] + cws[1][e] + cws[2][e] + cws[3][e];
            float ps = pws[0][e] + pws[1][e] + pws[2][e] + pws[3][e];
            ctrl[e] = ne;
            ctrl[32 + e] = off;
            int ntl = (ne + 127) >> 7;
            for (int i = 0; i < ntl; ++i) { tiles[nt] = make_int4(e, off + i * 128, off + ne, 0); ++nt; }
            off += ntl << 7;
            aux += ((float)ne * (1.f / 8192.f)) * (ps * (1.f / 4096.f));
        }
        ctrl[24] = nt;
        auxOut[0] = 8.f * aux;
    }
}

// ---------------------------------------------------------------- token placement (hierarchical, few atomics)
__global__ __launch_bounds__(256) void place_tokens(const int* __restrict__ topi,
                                                    const float* __restrict__ topw,
                                                    int* ctrl, int* __restrict__ perm,
                                                    float* __restrict__ pw) {
    __shared__ int lcnt[8], lbase[8];
    int tid = threadIdx.x;
    int t = blockIdx.x * 256 + tid;
    if (tid < 8) lcnt[tid] = 0;
    __syncthreads();
    int e0 = topi[2 * t], e1 = topi[2 * t + 1];
    int p0 = atomicAdd(&lcnt[e0], 1);     // LDS atomic
    int p1 = atomicAdd(&lcnt[e1], 1);
    __syncthreads();
    if (tid < 8) lbase[tid] = atomicAdd(&ctrl[16 + tid], lcnt[tid]);  // 8 global atomics/block
    __syncthreads();
    int g0 = ctrl[32 + e0] + lbase[e0] + p0;
    int g1 = ctrl[32 + e1] + lbase[e1] + p1;
    perm[g0] = t; pw[g0] = topw[2 * t];
    perm[g1] = t; pw[g1] = topw[2 * t + 1];
}

// ---------------------------------------------------------------- NT GEMM: C[M,N] = A[M,K] @ Bt[N,K]^T
// MODE 0: out bf16 (qkv)   MODE 1: out fp32 + residual (wo)
// MODE 2: gathered rows (perm) + silu -> bf16 (moe h1)
// MODE 3: direct rows + weighted atomicAdd scatter (moe out)
template <int MODE>
__global__ __launch_bounds__(256) void gemm_nt(const bf16* __restrict__ A,
                                               const bf16* __restrict__ Bt,
                                               int M, int N, int K,
                                               const float* __restrict__ xres,
                                               float* __restrict__ outF,
                                               bf16* __restrict__ outB,
                                               const int4* __restrict__ tiles,
                                               const int* __restrict__ ctrl,
                                               const int* __restrict__ perm,
                                               const float* __restrict__ pw) {
    __shared__ __align__(16) bf16 As[128 * 32];
    __shared__ __align__(16) bf16 Bs[128 * 32];
    __shared__ int sPerm[128];
    __shared__ float sPw[128];

    const int tid = threadIdx.x, lane = tid & 63, w = tid >> 6;
    const int wr = w >> 1, wc = w & 1, quad = lane >> 4, l16 = lane & 15;

    int m0 = 0, n0 = blockIdx.x * 128, row0 = 0, rowend = 0;
    if (MODE <= 1) {
        m0 = blockIdx.y * 128;
    } else {
        if ((int)blockIdx.y >= ctrl[24]) return;
        int4 td = tiles[blockIdx.y];
        row0 = td.y; rowend = td.z;
        Bt += (size_t)td.x * N * K;
        if (tid < 128) {
            int g = row0 + tid;
            int gs = (g < rowend) ? g : row0;   // clamp padded rows to a valid one
            sPerm[tid] = perm[gs];
            sPw[tid] = pw[gs];
        }
    }

    f32x4 acc[4][4] = {};

    for (int kt = 0; kt < K; kt += 32) {
        __syncthreads();
#pragma unroll
        for (int i = 0; i < 2; ++i) {           // stage A tile 128x32
            int c = i * 256 + tid;
            int r = c >> 2, koff = (c & 3) * 8;
            const bf16* gp;
            if (MODE == 2)      gp = A + (size_t)sPerm[r] * K + kt + koff;
            else if (MODE == 3) gp = A + (size_t)(row0 + r) * K + kt + koff;
            else                gp = A + (size_t)(m0 + r) * K + kt + koff;
            async_cp16(gp, (char*)As + (size_t)(i * 256 + w * 64) * 16);
        }
#pragma unroll
        for (int i = 0; i < 2; ++i) {           // stage B tile 128x32
            int c = i * 256 + tid;
            int r = c >> 2, koff = (c & 3) * 8;
            async_cp16(Bt + (size_t)(n0 + r) * K + kt + koff,
                       (char*)Bs + (size_t)(i * 256 + w * 64) * 16);
        }
        __syncthreads();

        bf16x8 af[4], bfr[4];
#pragma unroll
        for (int mi = 0; mi < 4; ++mi)
            af[mi] = *(const bf16x8*)(As + (wr * 64 + mi * 16 + l16) * 32 + quad * 8);
#pragma unroll
        for (int ni = 0; ni < 4; ++ni)
            bfr[ni] = *(const bf16x8*)(Bs + (wc * 64 + ni * 16 + l16) * 32 + quad * 8);
#pragma unroll
        for (int mi = 0; mi < 4; ++mi)
#pragma unroll
            for (int ni = 0; ni < 4; ++ni)
                acc[mi][ni] = __builtin_amdgcn_mfma_f32_16x16x32_bf16(af[mi], bfr[ni], acc[mi][ni], 0, 0, 0);
    }

#pragma unroll
    for (int mi = 0; mi < 4; ++mi)
#pragma unroll
        for (int ni = 0; ni < 4; ++ni)
#pragma unroll
            for (int r = 0; r < 4; ++r) {
                int lrow = wr * 64 + mi * 16 + quad * 4 + r;
                int col = n0 + wc * 64 + ni * 16 + l16;
                float v = acc[mi][ni][r];
                if (MODE == 0) {
                    outB[(size_t)(m0 + lrow) * N + col] = (bf16)v;
                } else if (MODE == 1) {
                    size_t idx = (size_t)(m0 + lrow) * N + col;
                    outF[idx] = v + xres[idx];
                } else if (MODE == 2) {
                    float sv = v / (1.f + __expf(-v));   // silu
                    outB[(size_t)(row0 + lrow) * N + col] = (bf16)sv;
                } else {
                    if (row0 + lrow < rowend)
                        atomicAdd(&outF[(size_t)sPerm[lrow] * N + col], v * sPw[lrow]);
                }
            }
}

__global__ void zero_ctrl(int* ctrl) { if (threadIdx.x < 64) ctrl[threadIdx.x] = 0; }

// ---------------------------------------------------------------- launch
extern "C" void kernel_launch(void* const* d_in, const int* in_sizes, int n_in,
                              void* d_out, int out_size, void* d_ws, size_t ws_size,
                              hipStream_t stream) {
    const float* x    = (const float*)d_in[0];
    const float* anw  = (const float*)d_in[1];
    const float* wqkv = (const float*)d_in[2];
    const float* wo   = (const float*)d_in[3];
    const float* fnw  = (const float*)d_in[4];
    const float* rw   = (const float*)d_in[5];
    const float* w1   = (const float*)d_in[6];
    const float* w2   = (const float*)d_in[7];
    float* out = (float*)d_out;

    char* ws = (char*)d_ws;
    size_t off = 0;
    auto alloc = [&](size_t bytes) -> char* {
        char* p = ws + off;
        off = (off + bytes + 255) & ~(size_t)255;
        return p;
    };
    bf16* wqkvT = (bf16*)alloc(2304ull * 768 * 2);
    bf16* woT   = (bf16*)alloc(768ull * 768 * 2);
    bf16* w1T   = (bf16*)alloc(8ull * 3072 * 768 * 2);
    bf16* w2T   = (bf16*)alloc(8ull * 768 * 3072 * 2);
    bf16* hbuf  = (bf16*)alloc(4096ull * 768 * 2);
    bf16* qkvb  = (bf16*)alloc(4096ull * 2304 * 2);
    bf16* qb    = (bf16*)alloc(24ull * 2048 * 64 * 2);
    bf16* kb    = (bf16*)alloc(24ull * 2048 * 64 * 2);
    bf16* vtb   = (bf16*)alloc(24ull * 64 * 2048 * 2);
    bf16* obuf  = (bf16*)alloc(4096ull * 768 * 2);
    bf16* hn    = (bf16*)alloc(4096ull * 768 * 2);
    int*  topi  = (int*)alloc(4096ull * 2 * 4);
    float* topw = (float*)alloc(4096ull * 2 * 4);
    float* probsb = (float*)alloc(4096ull * 8 * 4);
    int*  ctrl  = (int*)alloc(64 * 4);
    int4* tiles = (int4*)alloc(80 * 16);
    int*  perm  = (int*)alloc(9216 * 4);
    float* pwv  = (float*)alloc(9216 * 4);
    bf16* h1    = (bf16*)alloc(9216ull * 3072 * 2);
    (void)ws_size; (void)in_sizes; (void)n_in;

    zero_ctrl<<<1, 64, 0, stream>>>(ctrl);
    // weight transpose+casts to bf16 [N][K]
    transpose_cast<<<dim3(72, 24, 1), 256, 0, stream>>>(wqkv, wqkvT, 768, 2304);
    transpose_cast<<<dim3(24, 24, 1), 256, 0, stream>>>(wo, woT, 768, 768);
    transpose_cast<<<dim3(96, 24, 8), 256, 0, stream>>>(w1, w1T, 768, 3072);
    transpose_cast<<<dim3(24, 96, 8), 256, 0, stream>>>(w2, w2T, 3072, 768);
    // attention block
    rmsnorm_cast<<<4096, 256, 0, stream>>>(x, anw, hbuf);
    gemm_nt<0><<<dim3(18, 32), 256, 0, stream>>>(hbuf, wqkvT, 4096, 2304, 768,
                                                 nullptr, nullptr, qkvb, nullptr, nullptr, nullptr, nullptr);
    rope_kernel<<<dim3(32, 24), 256, 0, stream>>>(qkvb, qb, kb, vtb);
    attn_kernel<<<dim3(32, 24), 256, 0, stream>>>(qb, kb, vtb, obuf);
    gemm_nt<1><<<dim3(6, 32), 256, 0, stream>>>(obuf, woT, 4096, 768, 768,
                                                x, out, nullptr, nullptr, nullptr, nullptr, nullptr);
    // MoE block
    rms_router<<<4096, 256, 0, stream>>>(out, fnw, rw, hn, topi, topw, probsb);
    router_stats<<<1, 256, 0, stream>>>(probsb, topi, ctrl, tiles, out + (out_size - 1));
    place_tokens<<<16, 256, 0, stream>>>(topi, topw, ctrl, perm, pwv);
    gemm_nt<2><<<dim3(24, 72), 256, 0, stream>>>(hn, w1T, 0, 3072, 768,
                                                 nullptr, nullptr, h1, tiles, ctrl, perm, pwv);
    gemm_nt<3><<<dim3(6, 72), 256, 0, stream>>>(h1, w2T, 0, 768, 3072,
                                                nullptr, out, nullptr, tiles, ctrl, perm, pwv);
}

// Round 4
// 544.931 us; speedup vs baseline: 1.4754x; 1.1122x over previous
//
#include <hip/hip_runtime.h>
#include <cstdint>
#include <cstddef>

typedef __bf16 bf16;
typedef bf16 bf16x8 __attribute__((ext_vector_type(8)));
typedef float f32x4 __attribute__((ext_vector_type(4)));

// ---------------------------------------------------------------- helpers
__device__ __forceinline__ void async_cp16(const void* g, void* l) {
    // global -> LDS direct copy, 16B per lane. LDS dest semantics:
    // wave-uniform base (taken from lane 0) + lane*16.
    __builtin_amdgcn_global_load_lds(
        (const __attribute__((address_space(1))) unsigned int*)(unsigned long long)g,
        (__attribute__((address_space(3))) unsigned int*)(unsigned int)(unsigned long long)l,
        16, 0, 0);
}

// ---------------------------------------------------------------- transpose + cast fp32[R][C] -> bf16[C][R]
__global__ __launch_bounds__(256) void transpose_cast(const float* __restrict__ in,
                                                      bf16* __restrict__ out, int R, int C) {
    __shared__ float tile[32][33];
    int bz = blockIdx.z;
    in  += (size_t)bz * R * C;
    out += (size_t)bz * R * C;
    int c0 = blockIdx.x * 32, r0 = blockIdx.y * 32;
    int tx = threadIdx.x & 31, ty = threadIdx.x >> 5;   // 32 x 8
#pragma unroll
    for (int i = 0; i < 4; ++i)
        tile[ty + i * 8][tx] = in[(size_t)(r0 + ty + i * 8) * C + c0 + tx];
    __syncthreads();
#pragma unroll
    for (int i = 0; i < 4; ++i)
        out[(size_t)(c0 + ty + i * 8) * R + r0 + tx] = (bf16)tile[tx][ty + i * 8];
}

// ---------------------------------------------------------------- rmsnorm (fp32 -> bf16), H=768
__global__ __launch_bounds__(256) void rmsnorm_cast(const float* __restrict__ x,
                                                    const float* __restrict__ w,
                                                    bf16* __restrict__ out) {
    int row = blockIdx.x, tid = threadIdx.x;
    const float* xr = x + (size_t)row * 768;
    float v0 = xr[tid], v1 = xr[tid + 256], v2 = xr[tid + 512];
    float s = v0 * v0 + v1 * v1 + v2 * v2;
#pragma unroll
    for (int off = 32; off; off >>= 1) s += __shfl_xor(s, off, 64);
    __shared__ float red[4];
    if ((tid & 63) == 0) red[tid >> 6] = s;
    __syncthreads();
    float tot = red[0] + red[1] + red[2] + red[3];
    float rs = rsqrtf(tot * (1.f / 768.f) + 1e-6f);
    bf16* o = out + (size_t)row * 768;
    o[tid]       = (bf16)(v0 * rs * w[tid]);
    o[tid + 256] = (bf16)(v1 * rs * w[tid + 256]);
    o[tid + 512] = (bf16)(v2 * rs * w[tid + 512]);
}

// ---------------------------------------------------------------- RoPE + layout transform
// qkv bf16 [t][2304] -> q (pre-scaled by 0.125*log2e), k bf16 [bh][s][64], v -> vt bf16 [bh][d][s]
__global__ __launch_bounds__(256) void rope_kernel(const bf16* __restrict__ qkv,
                                                   bf16* __restrict__ qb,
                                                   bf16* __restrict__ kb,
                                                   bf16* __restrict__ vtb) {
    __shared__ float vs[64][65];
    const int tid = threadIdx.x;
    const int s0 = blockIdx.x * 64, bh = blockIdx.y;
    const int b = bh / 12, h = bh - b * 12;
    const float qscale = 0.18033688f;   // 0.125 * log2(e): softmax runs in exp2 domain
#pragma unroll
    for (int i = 0; i < 16; ++i) {
        int idx = i * 256 + tid;
        int sl = idx >> 6, d = idx & 63;
        int sg = s0 + sl;
        size_t base = ((size_t)b * 2048 + sg) * 2304;
        float qv = (float)qkv[base + h * 64 + d];
        float kv = (float)qkv[base + 768 + h * 64 + d];
        float vv = (float)qkv[base + 1536 + h * 64 + d];
        float qp = (float)qkv[base + h * 64 + (d ^ 32)];
        float kp = (float)qkv[base + 768 + h * 64 + (d ^ 32)];
        int jj = d & 31;
        float invf = __expf(-(float)jj * (9.210340371976184f / 32.f)); // 10000^(-j/32)
        float ang = (float)sg * invf;
        float cv, sv;
        __sincosf(ang, &sv, &cv);
        float rq = (d < 32) ? -qp : qp;
        float rk = (d < 32) ? -kp : kp;
        qb[((size_t)bh * 2048 + sg) * 64 + d] = (bf16)((qv * cv + rq * sv) * qscale);
        kb[((size_t)bh * 2048 + sg) * 64 + d] = (bf16)(kv * cv + rk * sv);
        vs[sl][d] = vv;
    }
    __syncthreads();
#pragma unroll
    for (int i = 0; i < 16; ++i) {
        int idx = i * 256 + tid;
        int d = idx >> 6, sl = idx & 63;
        vtb[(size_t)bh * 64 * 2048 + (size_t)d * 2048 + s0 + sl] = (bf16)vs[sl][d];
    }
}

// ---------------------------------------------------------------- flash attention (causal)
// grid (32 qtiles reversed, 24 bh), 256 thr. Q-tile 64, KV staged in PAIRS of 64.
// S computed TRANSPOSED (S^T = K Q^T) so each lane owns one q-row in-lane:
// softmax reductions are 15 VALU + 2 shfl instead of 4-step shfl chains.
__global__ __launch_bounds__(256) void attn_kernel(const bf16* __restrict__ qb,
                                                   const bf16* __restrict__ kb,
                                                   const bf16* __restrict__ vtb,
                                                   bf16* __restrict__ ob) {
    __shared__ __align__(16) bf16 Qs[2][64][32];        // 8 KB (staging only)
    __shared__ __align__(16) bf16 Ks[2][2][64][32];     // 16 KB: [tile][kk][kv][d]
    __shared__ __align__(16) bf16 Vts[2][2][64][32];    // 16 KB: [tile][kk][d][kv]
    __shared__ __align__(16) bf16 Ps[4][1024];          // 8 KB: per-wave P, chunk-swizzled

    const int tid = threadIdx.x, lane = tid & 63, w = tid >> 6;
    const int quad = lane >> 4, l16 = lane & 15;
    const int qt = 31 - (int)blockIdx.x, bh = blockIdx.y;   // largest-first scheduling
    const int q0 = qt * 64;
    const int b = bh / 12, h = bh - b * 12;

    const bf16* qhead = qb + (size_t)bh * 2048 * 64;
    const bf16* khead = kb + (size_t)bh * 2048 * 64;
    const bf16* vthead = vtb + (size_t)bh * 64 * 2048;

    // stage Q once (8 KB), then hoist fragments to registers
#pragma unroll
    for (int i = 0; i < 2; ++i) {
        int o = (i * 256 + tid) * 16;
        int kk = o >> 12, row = (o >> 6) & 63, el = (o & 63) >> 1;
        async_cp16(qhead + (size_t)(q0 + row) * 64 + kk * 32 + el,
                   (char*)Qs + (size_t)(i * 256 + w * 64) * 16);
    }
    __syncthreads();    // drains vmcnt: Q resident
    bf16x8 bq[2];
#pragma unroll
    for (int kk = 0; kk < 2; ++kk)
        bq[kk] = *(const bf16x8*)&Qs[kk][w * 16 + l16][quad * 8];

    f32x4 o_acc[4] = {};
    float m_st = -1e30f, l_st = 0.f;    // per-lane scalars: this lane's q-row = w*16+l16

    for (int j2 = 0; j2 <= qt; j2 += 2) {
        int nt2 = (j2 + 1 <= qt) ? 2 : 1;
        __syncthreads();    // previous pair fully consumed
#pragma unroll
        for (int t = 0; t < 2; ++t) {
            if (t >= nt2) break;
            int kv0 = (j2 + t) * 64;
#pragma unroll
            for (int i = 0; i < 2; ++i) {
                int o = (i * 256 + tid) * 16;
                int kk = o >> 12, row = (o >> 6) & 63, el = (o & 63) >> 1;
                async_cp16(khead + (size_t)(kv0 + row) * 64 + kk * 32 + el,
                           (char*)&Ks[t] + (size_t)(i * 256 + w * 64) * 16);
                async_cp16(vthead + (size_t)row * 2048 + kv0 + kk * 32 + el,
                           (char*)&Vts[t] + (size_t)(i * 256 + w * 64) * 16);
            }
        }
        __syncthreads();    // pair resident

#pragma unroll
        for (int t = 0; t < 2; ++t) {
            if (t >= nt2) break;

            // S^T = K Q^T : sacc[ni] rows kv=ni*16+quad*4+r, col q=l16
            f32x4 sacc[4] = {};
#pragma unroll
            for (int kk = 0; kk < 2; ++kk) {
                bf16x8 ak[4];
#pragma unroll
                for (int ni = 0; ni < 4; ++ni)
                    ak[ni] = *(const bf16x8*)&Ks[t][kk][ni * 16 + l16][quad * 8];
#pragma unroll
                for (int ni = 0; ni < 4; ++ni)
                    sacc[ni] = __builtin_amdgcn_mfma_f32_16x16x32_bf16(ak[ni], bq[kk], sacc[ni], 0, 0, 0);
            }

            // causal mask (diagonal tile only); scores already in exp2 units (Q pre-scaled)
            if (j2 + t == qt) {
                int ql = w * 16 + l16;
#pragma unroll
                for (int ni = 0; ni < 4; ++ni)
#pragma unroll
                    for (int r = 0; r < 4; ++r)
                        if (ni * 16 + quad * 4 + r > ql) sacc[ni][r] = -1e30f;
            }

            // online softmax: 16 values in-lane for this lane's q-row
            float mx = sacc[0][0];
#pragma unroll
            for (int ni = 0; ni < 4; ++ni)
#pragma unroll
                for (int r = 0; r < 4; ++r) mx = fmaxf(mx, sacc[ni][r]);
            mx = fmaxf(mx, __shfl_xor(mx, 16, 64));
            mx = fmaxf(mx, __shfl_xor(mx, 32, 64));
            float mnew = fmaxf(m_st, mx);
            float alpha = exp2f(m_st - mnew);
            m_st = mnew;
            float rsum = 0.f;
#pragma unroll
            for (int ni = 0; ni < 4; ++ni)
#pragma unroll
                for (int r = 0; r < 4; ++r) {
                    float pv = exp2f(sacc[ni][r] - mnew);
                    sacc[ni][r] = pv;
                    rsum += pv;
                }
            rsum += __shfl_xor(rsum, 16, 64);
            rsum += __shfl_xor(rsum, 32, 64);
            l_st = l_st * alpha + rsum;

            // broadcast alpha to O's C-layout rows (q = quad*4+r)
            float af[4];
#pragma unroll
            for (int r = 0; r < 4; ++r) af[r] = __shfl(alpha, quad * 4 + r, 64);
#pragma unroll
            for (int ni = 0; ni < 4; ++ni)
#pragma unroll
                for (int r = 0; r < 4; ++r) o_acc[ni][r] *= af[r];

            // P^T regs -> LDS in A-layout [q][kv], 16B-chunk XOR swizzle
            bf16* pb = Ps[w];
#pragma unroll
            for (int ni = 0; ni < 4; ++ni)
#pragma unroll
                for (int r = 0; r < 4; ++r) {
                    int kv = ni * 16 + quad * 4 + r;
                    int ch = (kv >> 3) ^ (l16 & 7);
                    pb[l16 * 64 + ch * 8 + (kv & 7)] = (bf16)sacc[ni][r];
                }

            // O += P V
#pragma unroll
            for (int kk = 0; kk < 2; ++kk) {
                int ch = (kk * 4 + quad) ^ (l16 & 7);
                bf16x8 ap = *(const bf16x8*)&pb[l16 * 64 + ch * 8];
                bf16x8 bv[4];
#pragma unroll
                for (int ni = 0; ni < 4; ++ni)
                    bv[ni] = *(const bf16x8*)&Vts[t][kk][ni * 16 + l16][quad * 8];
#pragma unroll
                for (int ni = 0; ni < 4; ++ni)
                    o_acc[ni] = __builtin_amdgcn_mfma_f32_16x16x32_bf16(ap, bv[ni], o_acc[ni], 0, 0, 0);
            }
        }
    }

    float lf[4];
#pragma unroll
    for (int r = 0; r < 4; ++r) lf[r] = 1.f / __shfl(l_st, quad * 4 + r, 64);
#pragma unroll
    for (int ni = 0; ni < 4; ++ni)
#pragma unroll
        for (int r = 0; r < 4; ++r) {
            int rowg = q0 + w * 16 + quad * 4 + r;
            size_t tk = (size_t)b * 2048 + rowg;
            ob[tk * 768 + h * 64 + ni * 16 + l16] = (bf16)(o_acc[ni][r] * lf[r]);
        }
}

// ---------------------------------------------------------------- fused rmsnorm2 + router (NO atomics)
__global__ __launch_bounds__(256) void rms_router(const float* __restrict__ x1,
                                                  const float* __restrict__ w,
                                                  const float* __restrict__ rw,
                                                  bf16* __restrict__ hn,
                                                  int* __restrict__ topi,
                                                  float* __restrict__ topw,
                                                  float* __restrict__ probsb) {
    __shared__ float hnf[768];
    __shared__ float part[256];
    __shared__ float lg[8];
    __shared__ float probs[8];
    __shared__ float red[4];
    int row = blockIdx.x, tid = threadIdx.x;
    const float* xr = x1 + (size_t)row * 768;
    float v0 = xr[tid], v1 = xr[tid + 256], v2 = xr[tid + 512];
    float s = v0 * v0 + v1 * v1 + v2 * v2;
#pragma unroll
    for (int off = 32; off; off >>= 1) s += __shfl_xor(s, off, 64);
    if ((tid & 63) == 0) red[tid >> 6] = s;
    __syncthreads();
    float tot = red[0] + red[1] + red[2] + red[3];
    float rs = rsqrtf(tot * (1.f / 768.f) + 1e-6f);
    float h0 = v0 * rs * w[tid], h1v = v1 * rs * w[tid + 256], h2v = v2 * rs * w[tid + 512];
    hnf[tid] = h0; hnf[tid + 256] = h1v; hnf[tid + 512] = h2v;
    bf16* o = hn + (size_t)row * 768;
    o[tid] = (bf16)h0; o[tid + 256] = (bf16)h1v; o[tid + 512] = (bf16)h2v;
    __syncthreads();
    // logits: 8 experts x 32 segments of 24
    int e = tid & 7, seg = tid >> 3;
    float p = 0.f;
#pragma unroll
    for (int j = 0; j < 24; ++j) { int k = seg * 24 + j; p += hnf[k] * rw[k * 8 + e]; }
    part[tid] = p;
    __syncthreads();
    if (tid < 8) { float a = 0.f; for (int sgi = 0; sgi < 32; ++sgi) a += part[sgi * 8 + tid]; lg[tid] = a; }
    __syncthreads();
    if (tid == 0) {
        float mx = lg[0];
        for (int i = 1; i < 8; ++i) mx = fmaxf(mx, lg[i]);
        float ssum = 0.f, ex[8];
        for (int i = 0; i < 8; ++i) { ex[i] = __expf(lg[i] - mx); ssum += ex[i]; }
        float inv = 1.f / ssum;
        for (int i = 0; i < 8; ++i) probs[i] = ex[i] * inv;
        int e0 = 0; float p0 = probs[0];
        for (int i = 1; i < 8; ++i) if (probs[i] > p0) { p0 = probs[i]; e0 = i; }
        int e1 = -1; float p1 = -1.f;
        for (int i = 0; i < 8; ++i) if (i != e0 && probs[i] > p1) { p1 = probs[i]; e1 = i; }
        float wsum = p0 + p1;
        topi[row * 2] = e0; topi[row * 2 + 1] = e1;
        topw[row * 2] = p0 / wsum; topw[row * 2 + 1] = p1 / wsum;
    }
    __syncthreads();
    if (tid < 8) probsb[(size_t)row * 8 + tid] = probs[tid];
}

// ---------------------------------------------------------------- router stats + tiles + aux (single block)
__global__ __launch_bounds__(256) void router_stats(const float* __restrict__ probsb,
                                                    const int* __restrict__ topi,
                                                    int* ctrl, int4* tiles, float* auxOut) {
    __shared__ float pws[4][8];
    __shared__ int cws[4][8];
    int tid = threadIdx.x;
    float s[8] = {};
    int cnt[8] = {};
    for (int t = tid; t < 4096; t += 256) {
        const float4* p = (const float4*)(probsb + (size_t)t * 8);
        float4 a = p[0], b = p[1];
        s[0] += a.x; s[1] += a.y; s[2] += a.z; s[3] += a.w;
        s[4] += b.x; s[5] += b.y; s[6] += b.z; s[7] += b.w;
        int e0 = topi[2 * t], e1 = topi[2 * t + 1];
#pragma unroll
        for (int e = 0; e < 8; ++e) cnt[e] += (e == e0) + (e == e1);
    }
#pragma unroll
    for (int e = 0; e < 8; ++e)
#pragma unroll
        for (int off = 32; off; off >>= 1) {
            s[e] += __shfl_xor(s[e], off, 64);
            cnt[e] += __shfl_xor(cnt[e], off, 64);
        }
    if ((tid & 63) == 0) {
#pragma unroll
        for (int e = 0; e < 8; ++e) { pws[tid >> 6][e] = s[e]; cws[tid >> 6][e] = cnt[e]; }
    }
    __syncthreads();
    if (tid == 0) {
        int off = 0, nt = 0;
        float aux = 0.f;
        for (int e = 0; e < 8; ++e) {
            int ne = cws[0][e] + cws[1][e] + cws[2][e] + cws[3][e];
            float ps = pws[0][e] + pws[1][e] + pws[2][e] + pws[3][e];
            ctrl[e] = ne;
            ctrl[32 + e] = off;
            int ntl = (ne + 127) >> 7;
            for (int i = 0; i < ntl; ++i) { tiles[nt] = make_int4(e, off + i * 128, off + ne, 0); ++nt; }
            off += ntl << 7;
            aux += ((float)ne * (1.f / 8192.f)) * (ps * (1.f / 4096.f));
        }
        ctrl[24] = nt;
        auxOut[0] = 8.f * aux;
    }
}

// ---------------------------------------------------------------- token placement (hierarchical, few atomics)
__global__ __launch_bounds__(256) void place_tokens(const int* __restrict__ topi,
                                                    const float* __restrict__ topw,
                                                    int* ctrl, int* __restrict__ perm,
                                                    float* __restrict__ pw) {
    __shared__ int lcnt[8], lbase[8];
    int tid = threadIdx.x;
    int t = blockIdx.x * 256 + tid;
    if (tid < 8) lcnt[tid] = 0;
    __syncthreads();
    int e0 = topi[2 * t], e1 = topi[2 * t + 1];
    int p0 = atomicAdd(&lcnt[e0], 1);     // LDS atomic
    int p1 = atomicAdd(&lcnt[e1], 1);
    __syncthreads();
    if (tid < 8) lbase[tid] = atomicAdd(&ctrl[16 + tid], lcnt[tid]);  // 8 global atomics/block
    __syncthreads();
    int g0 = ctrl[32 + e0] + lbase[e0] + p0;
    int g1 = ctrl[32 + e1] + lbase[e1] + p1;
    perm[g0] = t; pw[g0] = topw[2 * t];
    perm[g1] = t; pw[g1] = topw[2 * t + 1];
}

// ---------------------------------------------------------------- NT GEMM: C[M,N] = A[M,K] @ Bt[N,K]^T
// MODE 0: out bf16 (qkv)   MODE 1: out fp32 + residual (wo)
// MODE 2: gathered rows (perm) + silu -> bf16 (moe h1)
// MODE 3: direct rows + weighted atomicAdd scatter (moe out)
template <int MODE>
__global__ __launch_bounds__(256) void gemm_nt(const bf16* __restrict__ A,
                                               const bf16* __restrict__ Bt,
                                               int M, int N, int K,
                                               const float* __restrict__ xres,
                                               float* __restrict__ outF,
                                               bf16* __restrict__ outB,
                                               const int4* __restrict__ tiles,
                                               const int* __restrict__ ctrl,
                                               const int* __restrict__ perm,
                                               const float* __restrict__ pw) {
    __shared__ __align__(16) bf16 As[128 * 32];
    __shared__ __align__(16) bf16 Bs[128 * 32];
    __shared__ int sPerm[128];
    __shared__ float sPw[128];

    const int tid = threadIdx.x, lane = tid & 63, w = tid >> 6;
    const int wr = w >> 1, wc = w & 1, quad = lane >> 4, l16 = lane & 15;

    int m0 = 0, n0 = blockIdx.x * 128, row0 = 0, rowend = 0;
    if (MODE <= 1) {
        m0 = blockIdx.y * 128;
    } else {
        if ((int)blockIdx.y >= ctrl[24]) return;
        int4 td = tiles[blockIdx.y];
        row0 = td.y; rowend = td.z;
        Bt += (size_t)td.x * N * K;
        if (tid < 128) {
            int g = row0 + tid;
            int gs = (g < rowend) ? g : row0;   // clamp padded rows to a valid one
            sPerm[tid] = perm[gs];
            sPw[tid] = pw[gs];
        }
    }

    f32x4 acc[4][4] = {};

    for (int kt = 0; kt < K; kt += 32) {
        __syncthreads();
#pragma unroll
        for (int i = 0; i < 2; ++i) {           // stage A tile 128x32
            int c = i * 256 + tid;
            int r = c >> 2, koff = (c & 3) * 8;
            const bf16* gp;
            if (MODE == 2)      gp = A + (size_t)sPerm[r] * K + kt + koff;
            else if (MODE == 3) gp = A + (size_t)(row0 + r) * K + kt + koff;
            else                gp = A + (size_t)(m0 + r) * K + kt + koff;
            async_cp16(gp, (char*)As + (size_t)(i * 256 + w * 64) * 16);
        }
#pragma unroll
        for (int i = 0; i < 2; ++i) {           // stage B tile 128x32
            int c = i * 256 + tid;
            int r = c >> 2, koff = (c & 3) * 8;
            async_cp16(Bt + (size_t)(n0 + r) * K + kt + koff,
                       (char*)Bs + (size_t)(i * 256 + w * 64) * 16);
        }
        __syncthreads();

        bf16x8 af[4], bfr[4];
#pragma unroll
        for (int mi = 0; mi < 4; ++mi)
            af[mi] = *(const bf16x8*)(As + (wr * 64 + mi * 16 + l16) * 32 + quad * 8);
#pragma unroll
        for (int ni = 0; ni < 4; ++ni)
            bfr[ni] = *(const bf16x8*)(Bs + (wc * 64 + ni * 16 + l16) * 32 + quad * 8);
#pragma unroll
        for (int mi = 0; mi < 4; ++mi)
#pragma unroll
            for (int ni = 0; ni < 4; ++ni)
                acc[mi][ni] = __builtin_amdgcn_mfma_f32_16x16x32_bf16(af[mi], bfr[ni], acc[mi][ni], 0, 0, 0);
    }

#pragma unroll
    for (int mi = 0; mi < 4; ++mi)
#pragma unroll
        for (int ni = 0; ni < 4; ++ni)
#pragma unroll
            for (int r = 0; r < 4; ++r) {
                int lrow = wr * 64 + mi * 16 + quad * 4 + r;
                int col = n0 + wc * 64 + ni * 16 + l16;
                float v = acc[mi][ni][r];
                if (MODE == 0) {
                    outB[(size_t)(m0 + lrow) * N + col] = (bf16)v;
                } else if (MODE == 1) {
                    size_t idx = (size_t)(m0 + lrow) * N + col;
                    outF[idx] = v + xres[idx];
                } else if (MODE == 2) {
                    float sv = v / (1.f + __expf(-v));   // silu
                    outB[(size_t)(row0 + lrow) * N + col] = (bf16)sv;
                } else {
                    if (row0 + lrow < rowend)
                        atomicAdd(&outF[(size_t)sPerm[lrow] * N + col], v * sPw[lrow]);
                }
            }
}

__global__ void zero_ctrl(int* ctrl) { if (threadIdx.x < 64) ctrl[threadIdx.x] = 0; }

// ---------------------------------------------------------------- launch
extern "C" void kernel_launch(void* const* d_in, const int* in_sizes, int n_in,
                              void* d_out, int out_size, void* d_ws, size_t ws_size,
                              hipStream_t stream) {
    const float* x    = (const float*)d_in[0];
    const float* anw  = (const float*)d_in[1];
    const float* wqkv = (const float*)d_in[2];
    const float* wo   = (const float*)d_in[3];
    const float* fnw  = (const float*)d_in[4];
    const float* rw   = (const float*)d_in[5];
    const float* w1   = (const float*)d_in[6];
    const float* w2   = (const float*)d_in[7];
    float* out = (float*)d_out;

    char* ws = (char*)d_ws;
    size_t off = 0;
    auto alloc = [&](size_t bytes) -> char* {
        char* p = ws + off;
        off = (off + bytes + 255) & ~(size_t)255;
        return p;
    };
    bf16* wqkvT = (bf16*)alloc(2304ull * 768 * 2);
    bf16* woT   = (bf16*)alloc(768ull * 768 * 2);
    bf16* w1T   = (bf16*)alloc(8ull * 3072 * 768 * 2);
    bf16* w2T   = (bf16*)alloc(8ull * 768 * 3072 * 2);
    bf16* hbuf  = (bf16*)alloc(4096ull * 768 * 2);
    bf16* qkvb  = (bf16*)alloc(4096ull * 2304 * 2);
    bf16* qb    = (bf16*)alloc(24ull * 2048 * 64 * 2);
    bf16* kb    = (bf16*)alloc(24ull * 2048 * 64 * 2);
    bf16* vtb   = (bf16*)alloc(24ull * 64 * 2048 * 2);
    bf16* obuf  = (bf16*)alloc(4096ull * 768 * 2);
    bf16* hn    = (bf16*)alloc(4096ull * 768 * 2);
    int*  topi  = (int*)alloc(4096ull * 2 * 4);
    float* topw = (float*)alloc(4096ull * 2 * 4);
    float* probsb = (float*)alloc(4096ull * 8 * 4);
    int*  ctrl  = (int*)alloc(64 * 4);
    int4* tiles = (int4*)alloc(80 * 16);
    int*  perm  = (int*)alloc(9216 * 4);
    float* pwv  = (float*)alloc(9216 * 4);
    bf16* h1    = (bf16*)alloc(9216ull * 3072 * 2);
    (void)ws_size; (void)in_sizes; (void)n_in;

    zero_ctrl<<<1, 64, 0, stream>>>(ctrl);
    // weight transpose+casts to bf16 [N][K]
    transpose_cast<<<dim3(72, 24, 1), 256, 0, stream>>>(wqkv, wqkvT, 768, 2304);
    transpose_cast<<<dim3(24, 24, 1), 256, 0, stream>>>(wo, woT, 768, 768);
    transpose_cast<<<dim3(96, 24, 8), 256, 0, stream>>>(w1, w1T, 768, 3072);
    transpose_cast<<<dim3(24, 96, 8), 256, 0, stream>>>(w2, w2T, 3072, 768);
    // attention block
    rmsnorm_cast<<<4096, 256, 0, stream>>>(x, anw, hbuf);
    gemm_nt<0><<<dim3(18, 32), 256, 0, stream>>>(hbuf, wqkvT, 4096, 2304, 768,
                                                 nullptr, nullptr, qkvb, nullptr, nullptr, nullptr, nullptr);
    rope_kernel<<<dim3(32, 24), 256, 0, stream>>>(qkvb, qb, kb, vtb);
    attn_kernel<<<dim3(32, 24), 256, 0, stream>>>(qb, kb, vtb, obuf);
    gemm_nt<1><<<dim3(6, 32), 256, 0, stream>>>(obuf, woT, 4096, 768, 768,
                                                x, out, nullptr, nullptr, nullptr, nullptr, nullptr);
    // MoE block
    rms_router<<<4096, 256, 0, stream>>>(out, fnw, rw, hn, topi, topw, probsb);
    router_stats<<<1, 256, 0, stream>>>(probsb, topi, ctrl, tiles, out + (out_size - 1));
    place_tokens<<<16, 256, 0, stream>>>(topi, topw, ctrl, perm, pwv);
    gemm_nt<2><<<dim3(24, 72), 256, 0, stream>>>(hn, w1T, 0, 3072, 768,
                                                 nullptr, nullptr, h1, tiles, ctrl, perm, pwv);
    gemm_nt<3><<<dim3(6, 72), 256, 0, stream>>>(h1, w2T, 0, 768, 3072,
                                                nullptr, out, nullptr, tiles, ctrl, perm, pwv);
}

// Round 5
// 513.476 us; speedup vs baseline: 1.5658x; 1.0613x over previous
//
#include <hip/hip_runtime.h>
#include <cstdint>
#include <cstddef>

typedef __bf16 bf16;
typedef bf16 bf16x8 __attribute__((ext_vector_type(8)));
typedef float f32x4 __attribute__((ext_vector_type(4)));

// ---------------------------------------------------------------- helpers
__device__ __forceinline__ void async_cp16(const void* g, void* l) {
    // global -> LDS direct copy, 16B per lane. LDS dest semantics:
    // wave-uniform base (taken from lane 0) + lane*16.
    __builtin_amdgcn_global_load_lds(
        (const __attribute__((address_space(1))) unsigned int*)(unsigned long long)g,
        (__attribute__((address_space(3))) unsigned int*)(unsigned int)(unsigned long long)l,
        16, 0, 0);
}

// ---------------------------------------------------------------- transpose + cast fp32[R][C] -> bf16[C][R]
__global__ __launch_bounds__(256) void transpose_cast(const float* __restrict__ in,
                                                      bf16* __restrict__ out, int R, int C) {
    __shared__ float tile[32][33];
    int bz = blockIdx.z;
    in  += (size_t)bz * R * C;
    out += (size_t)bz * R * C;
    int c0 = blockIdx.x * 32, r0 = blockIdx.y * 32;
    int tx = threadIdx.x & 31, ty = threadIdx.x >> 5;   // 32 x 8
#pragma unroll
    for (int i = 0; i < 4; ++i)
        tile[ty + i * 8][tx] = in[(size_t)(r0 + ty + i * 8) * C + c0 + tx];
    __syncthreads();
#pragma unroll
    for (int i = 0; i < 4; ++i)
        out[(size_t)(c0 + ty + i * 8) * R + r0 + tx] = (bf16)tile[tx][ty + i * 8];
}

// ---------------------------------------------------------------- rmsnorm (fp32 -> bf16), H=768
__global__ __launch_bounds__(256) void rmsnorm_cast(const float* __restrict__ x,
                                                    const float* __restrict__ w,
                                                    bf16* __restrict__ out) {
    int row = blockIdx.x, tid = threadIdx.x;
    const float* xr = x + (size_t)row * 768;
    float v0 = xr[tid], v1 = xr[tid + 256], v2 = xr[tid + 512];
    float s = v0 * v0 + v1 * v1 + v2 * v2;
#pragma unroll
    for (int off = 32; off; off >>= 1) s += __shfl_xor(s, off, 64);
    __shared__ float red[4];
    if ((tid & 63) == 0) red[tid >> 6] = s;
    __syncthreads();
    float tot = red[0] + red[1] + red[2] + red[3];
    float rs = rsqrtf(tot * (1.f / 768.f) + 1e-6f);
    bf16* o = out + (size_t)row * 768;
    o[tid]       = (bf16)(v0 * rs * w[tid]);
    o[tid + 256] = (bf16)(v1 * rs * w[tid + 256]);
    o[tid + 512] = (bf16)(v2 * rs * w[tid + 512]);
}

// ---------------------------------------------------------------- RoPE + layout transform
// qkv bf16 [t][2304] -> q (pre-scaled by 0.125*log2e), k bf16 [bh][s][64], v -> vt bf16 [bh][d][s]
__global__ __launch_bounds__(256) void rope_kernel(const bf16* __restrict__ qkv,
                                                   bf16* __restrict__ qb,
                                                   bf16* __restrict__ kb,
                                                   bf16* __restrict__ vtb) {
    __shared__ float vs[64][65];
    const int tid = threadIdx.x;
    const int s0 = blockIdx.x * 64, bh = blockIdx.y;
    const int b = bh / 12, h = bh - b * 12;
    const float qscale = 0.18033688f;   // 0.125 * log2(e): softmax runs in exp2 domain
#pragma unroll
    for (int i = 0; i < 16; ++i) {
        int idx = i * 256 + tid;
        int sl = idx >> 6, d = idx & 63;
        int sg = s0 + sl;
        size_t base = ((size_t)b * 2048 + sg) * 2304;
        float qv = (float)qkv[base + h * 64 + d];
        float kv = (float)qkv[base + 768 + h * 64 + d];
        float vv = (float)qkv[base + 1536 + h * 64 + d];
        float qp = (float)qkv[base + h * 64 + (d ^ 32)];
        float kp = (float)qkv[base + 768 + h * 64 + (d ^ 32)];
        int jj = d & 31;
        float invf = __expf(-(float)jj * (9.210340371976184f / 32.f)); // 10000^(-j/32)
        float ang = (float)sg * invf;
        float cv, sv;
        __sincosf(ang, &sv, &cv);
        float rq = (d < 32) ? -qp : qp;
        float rk = (d < 32) ? -kp : kp;
        qb[((size_t)bh * 2048 + sg) * 64 + d] = (bf16)((qv * cv + rq * sv) * qscale);
        kb[((size_t)bh * 2048 + sg) * 64 + d] = (bf16)(kv * cv + rk * sv);
        vs[sl][d] = vv;
    }
    __syncthreads();
#pragma unroll
    for (int i = 0; i < 16; ++i) {
        int idx = i * 256 + tid;
        int d = idx >> 6, sl = idx & 63;
        vtb[(size_t)bh * 64 * 2048 + (size_t)d * 2048 + s0 + sl] = (bf16)vs[sl][d];
    }
}

// ---------------------------------------------------------------- flash attention (causal)
// grid (32 qtiles reversed, 24 bh), 256 thr. Q-tile 64, KV staged in PAIRS of 64.
// S computed TRANSPOSED (S^T = K Q^T) so each lane owns one q-row in-lane.
__global__ __launch_bounds__(256) void attn_kernel(const bf16* __restrict__ qb,
                                                   const bf16* __restrict__ kb,
                                                   const bf16* __restrict__ vtb,
                                                   bf16* __restrict__ ob) {
    __shared__ __align__(16) bf16 Qs[2][64][32];        // 8 KB (staging only)
    __shared__ __align__(16) bf16 Ks[2][2][64][32];     // 16 KB: [tile][kk][kv][d]
    __shared__ __align__(16) bf16 Vts[2][2][64][32];    // 16 KB: [tile][kk][d][kv]
    __shared__ __align__(16) bf16 Ps[4][1024];          // 8 KB: per-wave P, chunk-swizzled

    const int tid = threadIdx.x, lane = tid & 63, w = tid >> 6;
    const int quad = lane >> 4, l16 = lane & 15;
    const int qt = 31 - (int)blockIdx.x, bh = blockIdx.y;   // largest-first scheduling
    const int q0 = qt * 64;
    const int b = bh / 12, h = bh - b * 12;

    const bf16* qhead = qb + (size_t)bh * 2048 * 64;
    const bf16* khead = kb + (size_t)bh * 2048 * 64;
    const bf16* vthead = vtb + (size_t)bh * 64 * 2048;

    // stage Q once (8 KB), then hoist fragments to registers
#pragma unroll
    for (int i = 0; i < 2; ++i) {
        int o = (i * 256 + tid) * 16;
        int kk = o >> 12, row = (o >> 6) & 63, el = (o & 63) >> 1;
        async_cp16(qhead + (size_t)(q0 + row) * 64 + kk * 32 + el,
                   (char*)Qs + (size_t)(i * 256 + w * 64) * 16);
    }
    __syncthreads();    // drains vmcnt: Q resident
    bf16x8 bq[2];
#pragma unroll
    for (int kk = 0; kk < 2; ++kk)
        bq[kk] = *(const bf16x8*)&Qs[kk][w * 16 + l16][quad * 8];

    f32x4 o_acc[4] = {};
    float m_st = -1e30f, l_st = 0.f;    // per-lane scalars: this lane's q-row = w*16+l16

    for (int j2 = 0; j2 <= qt; j2 += 2) {
        int nt2 = (j2 + 1 <= qt) ? 2 : 1;
        __syncthreads();    // previous pair fully consumed
#pragma unroll
        for (int t = 0; t < 2; ++t) {
            if (t >= nt2) break;
            int kv0 = (j2 + t) * 64;
#pragma unroll
            for (int i = 0; i < 2; ++i) {
                int o = (i * 256 + tid) * 16;
                int kk = o >> 12, row = (o >> 6) & 63, el = (o & 63) >> 1;
                async_cp16(khead + (size_t)(kv0 + row) * 64 + kk * 32 + el,
                           (char*)&Ks[t] + (size_t)(i * 256 + w * 64) * 16);
                async_cp16(vthead + (size_t)row * 2048 + kv0 + kk * 32 + el,
                           (char*)&Vts[t] + (size_t)(i * 256 + w * 64) * 16);
            }
        }
        __syncthreads();    // pair resident

#pragma unroll
        for (int t = 0; t < 2; ++t) {
            if (t >= nt2) break;

            // S^T = K Q^T : sacc[ni] rows kv=ni*16+quad*4+r, col q=l16
            f32x4 sacc[4] = {};
#pragma unroll
            for (int kk = 0; kk < 2; ++kk) {
                bf16x8 ak[4];
#pragma unroll
                for (int ni = 0; ni < 4; ++ni)
                    ak[ni] = *(const bf16x8*)&Ks[t][kk][ni * 16 + l16][quad * 8];
#pragma unroll
                for (int ni = 0; ni < 4; ++ni)
                    sacc[ni] = __builtin_amdgcn_mfma_f32_16x16x32_bf16(ak[ni], bq[kk], sacc[ni], 0, 0, 0);
            }

            // causal mask (diagonal tile only); scores already in exp2 units (Q pre-scaled)
            if (j2 + t == qt) {
                int ql = w * 16 + l16;
#pragma unroll
                for (int ni = 0; ni < 4; ++ni)
#pragma unroll
                    for (int r = 0; r < 4; ++r)
                        if (ni * 16 + quad * 4 + r > ql) sacc[ni][r] = -1e30f;
            }

            // online softmax: 16 values in-lane for this lane's q-row
            float mx = sacc[0][0];
#pragma unroll
            for (int ni = 0; ni < 4; ++ni)
#pragma unroll
                for (int r = 0; r < 4; ++r) mx = fmaxf(mx, sacc[ni][r]);
            mx = fmaxf(mx, __shfl_xor(mx, 16, 64));
            mx = fmaxf(mx, __shfl_xor(mx, 32, 64));
            float mnew = fmaxf(m_st, mx);
            float alpha = exp2f(m_st - mnew);
            m_st = mnew;
            float rsum = 0.f;
#pragma unroll
            for (int ni = 0; ni < 4; ++ni)
#pragma unroll
                for (int r = 0; r < 4; ++r) {
                    float pv = exp2f(sacc[ni][r] - mnew);
                    sacc[ni][r] = pv;
                    rsum += pv;
                }
            rsum += __shfl_xor(rsum, 16, 64);
            rsum += __shfl_xor(rsum, 32, 64);
            l_st = l_st * alpha + rsum;

            // broadcast alpha to O's C-layout rows (q = quad*4+r)
            float af[4];
#pragma unroll
            for (int r = 0; r < 4; ++r) af[r] = __shfl(alpha, quad * 4 + r, 64);
#pragma unroll
            for (int ni = 0; ni < 4; ++ni)
#pragma unroll
                for (int r = 0; r < 4; ++r) o_acc[ni][r] *= af[r];

            // P^T regs -> LDS in A-layout [q][kv], 16B-chunk XOR swizzle
            bf16* pb = Ps[w];
#pragma unroll
            for (int ni = 0; ni < 4; ++ni)
#pragma unroll
                for (int r = 0; r < 4; ++r) {
                    int kv = ni * 16 + quad * 4 + r;
                    int ch = (kv >> 3) ^ (l16 & 7);
                    pb[l16 * 64 + ch * 8 + (kv & 7)] = (bf16)sacc[ni][r];
                }

            // O += P V
#pragma unroll
            for (int kk = 0; kk < 2; ++kk) {
                int ch = (kk * 4 + quad) ^ (l16 & 7);
                bf16x8 ap = *(const bf16x8*)&pb[l16 * 64 + ch * 8];
                bf16x8 bv[4];
#pragma unroll
                for (int ni = 0; ni < 4; ++ni)
                    bv[ni] = *(const bf16x8*)&Vts[t][kk][ni * 16 + l16][quad * 8];
#pragma unroll
                for (int ni = 0; ni < 4; ++ni)
                    o_acc[ni] = __builtin_amdgcn_mfma_f32_16x16x32_bf16(ap, bv[ni], o_acc[ni], 0, 0, 0);
            }
        }
    }

    float lf[4];
#pragma unroll
    for (int r = 0; r < 4; ++r) lf[r] = 1.f / __shfl(l_st, quad * 4 + r, 64);
#pragma unroll
    for (int ni = 0; ni < 4; ++ni)
#pragma unroll
        for (int r = 0; r < 4; ++r) {
            int rowg = q0 + w * 16 + quad * 4 + r;
            size_t tk = (size_t)b * 2048 + rowg;
            ob[tk * 768 + h * 64 + ni * 16 + l16] = (bf16)(o_acc[ni][r] * lf[r]);
        }
}

// ---------------------------------------------------------------- fused rmsnorm2 + router (NO atomics)
__global__ __launch_bounds__(256) void rms_router(const float* __restrict__ x1,
                                                  const float* __restrict__ w,
                                                  const float* __restrict__ rw,
                                                  bf16* __restrict__ hn,
                                                  int* __restrict__ topi,
                                                  float* __restrict__ topw,
                                                  float* __restrict__ probsb) {
    __shared__ float hnf[768];
    __shared__ float part[256];
    __shared__ float lg[8];
    __shared__ float probs[8];
    __shared__ float red[4];
    int row = blockIdx.x, tid = threadIdx.x;
    const float* xr = x1 + (size_t)row * 768;
    float v0 = xr[tid], v1 = xr[tid + 256], v2 = xr[tid + 512];
    float s = v0 * v0 + v1 * v1 + v2 * v2;
#pragma unroll
    for (int off = 32; off; off >>= 1) s += __shfl_xor(s, off, 64);
    if ((tid & 63) == 0) red[tid >> 6] = s;
    __syncthreads();
    float tot = red[0] + red[1] + red[2] + red[3];
    float rs = rsqrtf(tot * (1.f / 768.f) + 1e-6f);
    float h0 = v0 * rs * w[tid], h1v = v1 * rs * w[tid + 256], h2v = v2 * rs * w[tid + 512];
    hnf[tid] = h0; hnf[tid + 256] = h1v; hnf[tid + 512] = h2v;
    bf16* o = hn + (size_t)row * 768;
    o[tid] = (bf16)h0; o[tid + 256] = (bf16)h1v; o[tid + 512] = (bf16)h2v;
    __syncthreads();
    // logits: 8 experts x 32 segments of 24
    int e = tid & 7, seg = tid >> 3;
    float p = 0.f;
#pragma unroll
    for (int j = 0; j < 24; ++j) { int k = seg * 24 + j; p += hnf[k] * rw[k * 8 + e]; }
    part[tid] = p;
    __syncthreads();
    if (tid < 8) { float a = 0.f; for (int sgi = 0; sgi < 32; ++sgi) a += part[sgi * 8 + tid]; lg[tid] = a; }
    __syncthreads();
    if (tid == 0) {
        float mx = lg[0];
        for (int i = 1; i < 8; ++i) mx = fmaxf(mx, lg[i]);
        float ssum = 0.f, ex[8];
        for (int i = 0; i < 8; ++i) { ex[i] = __expf(lg[i] - mx); ssum += ex[i]; }
        float inv = 1.f / ssum;
        for (int i = 0; i < 8; ++i) probs[i] = ex[i] * inv;
        int e0 = 0; float p0 = probs[0];
        for (int i = 1; i < 8; ++i) if (probs[i] > p0) { p0 = probs[i]; e0 = i; }
        int e1 = -1; float p1 = -1.f;
        for (int i = 0; i < 8; ++i) if (i != e0 && probs[i] > p1) { p1 = probs[i]; e1 = i; }
        float wsum = p0 + p1;
        topi[row * 2] = e0; topi[row * 2 + 1] = e1;
        topw[row * 2] = p0 / wsum; topw[row * 2 + 1] = p1 / wsum;
    }
    __syncthreads();
    if (tid < 8) probsb[(size_t)row * 8 + tid] = probs[tid];
}

// ---------------------------------------------------------------- router stats + tiles + aux (single block)
__global__ __launch_bounds__(256) void router_stats(const float* __restrict__ probsb,
                                                    const int* __restrict__ topi,
                                                    int* ctrl, int4* tiles, float* auxOut) {
    __shared__ float pws[4][8];
    __shared__ int cws[4][8];
    int tid = threadIdx.x;
    float s[8] = {};
    int cnt[8] = {};
    for (int t = tid; t < 4096; t += 256) {
        const float4* p = (const float4*)(probsb + (size_t)t * 8);
        float4 a = p[0], b = p[1];
        s[0] += a.x; s[1] += a.y; s[2] += a.z; s[3] += a.w;
        s[4] += b.x; s[5] += b.y; s[6] += b.z; s[7] += b.w;
        int e0 = topi[2 * t], e1 = topi[2 * t + 1];
#pragma unroll
        for (int e = 0; e < 8; ++e) cnt[e] += (e == e0) + (e == e1);
    }
#pragma unroll
    for (int e = 0; e < 8; ++e)
#pragma unroll
        for (int off = 32; off; off >>= 1) {
            s[e] += __shfl_xor(s[e], off, 64);
            cnt[e] += __shfl_xor(cnt[e], off, 64);
        }
    if ((tid & 63) == 0) {
#pragma unroll
        for (int e = 0; e < 8; ++e) { pws[tid >> 6][e] = s[e]; cws[tid >> 6][e] = cnt[e]; }
    }
    __syncthreads();
    if (tid == 0) {
        int off = 0, nt = 0;
        float aux = 0.f;
        for (int e = 0; e < 8; ++e) {
            int ne = cws[0][e] + cws[1][e] + cws[2][e] + cws[3][e];
            float ps = pws[0][e] + pws[1][e] + pws[2][e] + pws[3][e];
            ctrl[e] = ne;
            ctrl[32 + e] = off;
            int ntl = (ne + 127) >> 7;
            for (int i = 0; i < ntl; ++i) { tiles[nt] = make_int4(e, off + i * 128, off + ne, 0); ++nt; }
            off += ntl << 7;
            aux += ((float)ne * (1.f / 8192.f)) * (ps * (1.f / 4096.f));
        }
        ctrl[24] = nt;
        auxOut[0] = 8.f * aux;
    }
}

// ---------------------------------------------------------------- token placement (hierarchical, few atomics)
__global__ __launch_bounds__(256) void place_tokens(const int* __restrict__ topi,
                                                    int* ctrl, int* __restrict__ perm,
                                                    int* __restrict__ tokslot) {
    __shared__ int lcnt[8], lbase[8];
    int tid = threadIdx.x;
    int t = blockIdx.x * 256 + tid;
    if (tid < 8) lcnt[tid] = 0;
    __syncthreads();
    int e0 = topi[2 * t], e1 = topi[2 * t + 1];
    int p0 = atomicAdd(&lcnt[e0], 1);     // LDS atomic
    int p1 = atomicAdd(&lcnt[e1], 1);
    __syncthreads();
    if (tid < 8) lbase[tid] = atomicAdd(&ctrl[16 + tid], lcnt[tid]);  // 8 global atomics/block
    __syncthreads();
    int g0 = ctrl[32 + e0] + lbase[e0] + p0;
    int g1 = ctrl[32 + e1] + lbase[e1] + p1;
    perm[g0] = t; perm[g1] = t;
    tokslot[2 * t] = g0; tokslot[2 * t + 1] = g1;
}

// ---------------------------------------------------------------- final combine: out += w0*h2[s0] + w1*h2[s1]
__global__ __launch_bounds__(256) void moe_combine(const bf16* __restrict__ h2,
                                                   const int* __restrict__ tokslot,
                                                   const float* __restrict__ topw,
                                                   float* __restrict__ out) {
    int t = blockIdx.x, tid = threadIdx.x;
    int s0 = tokslot[2 * t], s1 = tokslot[2 * t + 1];
    float w0 = topw[2 * t], w1 = topw[2 * t + 1];
    const bf16* r0 = h2 + (size_t)s0 * 768;
    const bf16* r1 = h2 + (size_t)s1 * 768;
    float* o = out + (size_t)t * 768;
#pragma unroll
    for (int i = 0; i < 3; ++i) {
        int c = i * 256 + tid;
        o[c] += w0 * (float)r0[c] + w1 * (float)r1[c];
    }
}

// ---------------------------------------------------------------- NT GEMM: C[M,N] = A[M,K] @ Bt[N,K]^T
// Double-buffered LDS K-loop: stage round k+1 before computing round k; one barrier/round.
// MODE 0: out bf16 (qkv)   MODE 1: out fp32 + residual (wo)
// MODE 2: gathered rows (perm) + silu -> bf16 (moe h1)
// MODE 3: direct rows -> bf16 h2 slot rows (no atomics)
template <int MODE>
__global__ __launch_bounds__(256) void gemm_nt(const bf16* __restrict__ A,
                                               const bf16* __restrict__ Bt,
                                               int M, int N, int K,
                                               const float* __restrict__ xres,
                                               float* __restrict__ outF,
                                               bf16* __restrict__ outB,
                                               const int4* __restrict__ tiles,
                                               const int* __restrict__ ctrl,
                                               const int* __restrict__ perm) {
    __shared__ __align__(16) bf16 As[2][128 * 32];
    __shared__ __align__(16) bf16 Bs[2][128 * 32];
    __shared__ int sPerm[128];

    const int tid = threadIdx.x, lane = tid & 63, w = tid >> 6;
    const int wr = w >> 1, wc = w & 1, quad = lane >> 4, l16 = lane & 15;

    int m0 = 0, n0 = blockIdx.x * 128, row0 = 0;
    if (MODE <= 1) {
        m0 = blockIdx.y * 128;
    } else {
        if ((int)blockIdx.y >= ctrl[24]) return;
        int4 td = tiles[blockIdx.y];
        row0 = td.y;
        int rowend = td.z;
        Bt += (size_t)td.x * N * K;
        if (MODE == 2 && tid < 128) {
            int g = row0 + tid;
            int gs = (g < rowend) ? g : row0;   // clamp padded rows to a valid one
            sPerm[tid] = perm[gs];
        }
        if (MODE == 2) __syncthreads();          // sPerm visible before first staging
    }

    auto stage = [&](int buf, int kt) {
#pragma unroll
        for (int i = 0; i < 2; ++i) {
            int c = i * 256 + tid;
            int r = c >> 2, koff = (c & 3) * 8;
            const bf16* gp;
            if (MODE == 2)      gp = A + (size_t)sPerm[r] * K + kt + koff;
            else if (MODE == 3) gp = A + (size_t)(row0 + r) * K + kt + koff;
            else                gp = A + (size_t)(m0 + r) * K + kt + koff;
            async_cp16(gp, (char*)As[buf] + (size_t)(i * 256 + w * 64) * 16);
            async_cp16(Bt + (size_t)(n0 + r) * K + kt + koff,
                       (char*)Bs[buf] + (size_t)(i * 256 + w * 64) * 16);
        }
    };

    f32x4 acc[4][4] = {};
    const int nIt = K >> 5;
    stage(0, 0);

    for (int it = 0; it < nIt; ++it) {
        const int cur = it & 1;
        __syncthreads();                         // cur staged (vmcnt drain); prev reads of cur^1 done
        if (it + 1 < nIt) stage(cur ^ 1, (it + 1) << 5);

        bf16x8 af[4], bfr[4];
#pragma unroll
        for (int mi = 0; mi < 4; ++mi)
            af[mi] = *(const bf16x8*)(As[cur] + (wr * 64 + mi * 16 + l16) * 32 + quad * 8);
#pragma unroll
        for (int ni = 0; ni < 4; ++ni)
            bfr[ni] = *(const bf16x8*)(Bs[cur] + (wc * 64 + ni * 16 + l16) * 32 + quad * 8);
#pragma unroll
        for (int mi = 0; mi < 4; ++mi)
#pragma unroll
            for (int ni = 0; ni < 4; ++ni)
                acc[mi][ni] = __builtin_amdgcn_mfma_f32_16x16x32_bf16(af[mi], bfr[ni], acc[mi][ni], 0, 0, 0);
    }

#pragma unroll
    for (int mi = 0; mi < 4; ++mi)
#pragma unroll
        for (int ni = 0; ni < 4; ++ni)
#pragma unroll
            for (int r = 0; r < 4; ++r) {
                int lrow = wr * 64 + mi * 16 + quad * 4 + r;
                int col = n0 + wc * 64 + ni * 16 + l16;
                float v = acc[mi][ni][r];
                if (MODE == 0) {
                    outB[(size_t)(m0 + lrow) * N + col] = (bf16)v;
                } else if (MODE == 1) {
                    size_t idx = (size_t)(m0 + lrow) * N + col;
                    outF[idx] = v + xres[idx];
                } else if (MODE == 2) {
                    float sv = v / (1.f + __expf(-v));   // silu
                    outB[(size_t)(row0 + lrow) * N + col] = (bf16)sv;
                } else {
                    outB[(size_t)(row0 + lrow) * N + col] = (bf16)v;   // h2 slot row
                }
            }
}

__global__ void zero_ctrl(int* ctrl) { if (threadIdx.x < 64) ctrl[threadIdx.x] = 0; }

// ---------------------------------------------------------------- launch
extern "C" void kernel_launch(void* const* d_in, const int* in_sizes, int n_in,
                              void* d_out, int out_size, void* d_ws, size_t ws_size,
                              hipStream_t stream) {
    const float* x    = (const float*)d_in[0];
    const float* anw  = (const float*)d_in[1];
    const float* wqkv = (const float*)d_in[2];
    const float* wo   = (const float*)d_in[3];
    const float* fnw  = (const float*)d_in[4];
    const float* rw   = (const float*)d_in[5];
    const float* w1   = (const float*)d_in[6];
    const float* w2   = (const float*)d_in[7];
    float* out = (float*)d_out;

    char* ws = (char*)d_ws;
    size_t off = 0;
    auto alloc = [&](size_t bytes) -> char* {
        char* p = ws + off;
        off = (off + bytes + 255) & ~(size_t)255;
        return p;
    };
    bf16* wqkvT = (bf16*)alloc(2304ull * 768 * 2);
    bf16* woT   = (bf16*)alloc(768ull * 768 * 2);
    bf16* w1T   = (bf16*)alloc(8ull * 3072 * 768 * 2);
    bf16* w2T   = (bf16*)alloc(8ull * 768 * 3072 * 2);
    bf16* hbuf  = (bf16*)alloc(4096ull * 768 * 2);
    bf16* qkvb  = (bf16*)alloc(4096ull * 2304 * 2);   // reused as h2 slot buffer in MoE phase
    bf16* qb    = (bf16*)alloc(24ull * 2048 * 64 * 2);
    bf16* kb    = (bf16*)alloc(24ull * 2048 * 64 * 2);
    bf16* vtb   = (bf16*)alloc(24ull * 64 * 2048 * 2);
    bf16* obuf  = (bf16*)alloc(4096ull * 768 * 2);
    bf16* hn    = (bf16*)alloc(4096ull * 768 * 2);
    int*  topi  = (int*)alloc(4096ull * 2 * 4);
    float* topw = (float*)alloc(4096ull * 2 * 4);
    float* probsb = (float*)alloc(4096ull * 8 * 4);
    int*  ctrl  = (int*)alloc(64 * 4);
    int4* tiles = (int4*)alloc(80 * 16);
    int*  perm  = (int*)alloc(9216 * 4);
    int*  tokslot = (int*)alloc(4096ull * 2 * 4);
    bf16* h1    = (bf16*)alloc(9216ull * 3072 * 2);
    bf16* h2    = qkvb;                                // alias: qkvb dead after rope
    (void)ws_size; (void)in_sizes; (void)n_in;

    zero_ctrl<<<1, 64, 0, stream>>>(ctrl);
    // weight transpose+casts to bf16 [N][K]
    transpose_cast<<<dim3(72, 24, 1), 256, 0, stream>>>(wqkv, wqkvT, 768, 2304);
    transpose_cast<<<dim3(24, 24, 1), 256, 0, stream>>>(wo, woT, 768, 768);
    transpose_cast<<<dim3(96, 24, 8), 256, 0, stream>>>(w1, w1T, 768, 3072);
    transpose_cast<<<dim3(24, 96, 8), 256, 0, stream>>>(w2, w2T, 3072, 768);
    // attention block
    rmsnorm_cast<<<4096, 256, 0, stream>>>(x, anw, hbuf);
    gemm_nt<0><<<dim3(18, 32), 256, 0, stream>>>(hbuf, wqkvT, 4096, 2304, 768,
                                                 nullptr, nullptr, qkvb, nullptr, nullptr, nullptr);
    rope_kernel<<<dim3(32, 24), 256, 0, stream>>>(qkvb, qb, kb, vtb);
    attn_kernel<<<dim3(32, 24), 256, 0, stream>>>(qb, kb, vtb, obuf);
    gemm_nt<1><<<dim3(6, 32), 256, 0, stream>>>(obuf, woT, 4096, 768, 768,
                                                x, out, nullptr, nullptr, nullptr, nullptr);
    // MoE block
    rms_router<<<4096, 256, 0, stream>>>(out, fnw, rw, hn, topi, topw, probsb);
    router_stats<<<1, 256, 0, stream>>>(probsb, topi, ctrl, tiles, out + (out_size - 1));
    place_tokens<<<16, 256, 0, stream>>>(topi, ctrl, perm, tokslot);
    gemm_nt<2><<<dim3(24, 72), 256, 0, stream>>>(hn, w1T, 0, 3072, 768,
                                                 nullptr, nullptr, h1, tiles, ctrl, perm);
    gemm_nt<3><<<dim3(6, 72), 256, 0, stream>>>(h1, w2T, 0, 768, 3072,
                                                nullptr, nullptr, h2, tiles, ctrl, perm);
    moe_combine<<<4096, 256, 0, stream>>>(h2, tokslot, topw, out);
}

// Round 6
// 496.955 us; speedup vs baseline: 1.6178x; 1.0332x over previous
//
#include <hip/hip_runtime.h>
#include <cstdint>
#include <cstddef>

typedef __bf16 bf16;
typedef bf16 bf16x8 __attribute__((ext_vector_type(8)));
typedef float f32x4 __attribute__((ext_vector_type(4)));

// ---------------------------------------------------------------- helpers
__device__ __forceinline__ void async_cp16(const void* g, void* l) {
    __builtin_amdgcn_global_load_lds(
        (const __attribute__((address_space(1))) unsigned int*)(unsigned long long)g,
        (__attribute__((address_space(3))) unsigned int*)(unsigned int)(unsigned long long)l,
        16, 0, 0);
}

// ---------------------------------------------------------------- transpose + cast fp32[R][C] -> bf16[C][R]
__global__ __launch_bounds__(256) void transpose_cast(const float* __restrict__ in,
                                                      bf16* __restrict__ out, int R, int C) {
    __shared__ float tile[32][33];
    int bz = blockIdx.z;
    in  += (size_t)bz * R * C;
    out += (size_t)bz * R * C;
    int c0 = blockIdx.x * 32, r0 = blockIdx.y * 32;
    int tx = threadIdx.x & 31, ty = threadIdx.x >> 5;   // 32 x 8
#pragma unroll
    for (int i = 0; i < 4; ++i)
        tile[ty + i * 8][tx] = in[(size_t)(r0 + ty + i * 8) * C + c0 + tx];
    __syncthreads();
#pragma unroll
    for (int i = 0; i < 4; ++i)
        out[(size_t)(c0 + ty + i * 8) * R + r0 + tx] = (bf16)tile[tx][ty + i * 8];
}

// ---------------------------------------------------------------- rmsnorm (fp32 -> bf16), H=768
__global__ __launch_bounds__(256) void rmsnorm_cast(const float* __restrict__ x,
                                                    const float* __restrict__ w,
                                                    bf16* __restrict__ out) {
    int row = blockIdx.x, tid = threadIdx.x;
    const float* xr = x + (size_t)row * 768;
    float v0 = xr[tid], v1 = xr[tid + 256], v2 = xr[tid + 512];
    float s = v0 * v0 + v1 * v1 + v2 * v2;
#pragma unroll
    for (int off = 32; off; off >>= 1) s += __shfl_xor(s, off, 64);
    __shared__ float red[4];
    if ((tid & 63) == 0) red[tid >> 6] = s;
    __syncthreads();
    float tot = red[0] + red[1] + red[2] + red[3];
    float rs = rsqrtf(tot * (1.f / 768.f) + 1e-6f);
    bf16* o = out + (size_t)row * 768;
    o[tid]       = (bf16)(v0 * rs * w[tid]);
    o[tid + 256] = (bf16)(v1 * rs * w[tid + 256]);
    o[tid + 512] = (bf16)(v2 * rs * w[tid + 512]);
}

// ---------------------------------------------------------------- RoPE + layout transform
__global__ __launch_bounds__(256) void rope_kernel(const bf16* __restrict__ qkv,
                                                   bf16* __restrict__ qb,
                                                   bf16* __restrict__ kb,
                                                   bf16* __restrict__ vtb) {
    __shared__ float vs[64][65];
    const int tid = threadIdx.x;
    const int s0 = blockIdx.x * 64, bh = blockIdx.y;
    const int b = bh / 12, h = bh - b * 12;
    const float qscale = 0.18033688f;   // 0.125 * log2(e): softmax runs in exp2 domain
#pragma unroll
    for (int i = 0; i < 16; ++i) {
        int idx = i * 256 + tid;
        int sl = idx >> 6, d = idx & 63;
        int sg = s0 + sl;
        size_t base = ((size_t)b * 2048 + sg) * 2304;
        float qv = (float)qkv[base + h * 64 + d];
        float kv = (float)qkv[base + 768 + h * 64 + d];
        float vv = (float)qkv[base + 1536 + h * 64 + d];
        float qp = (float)qkv[base + h * 64 + (d ^ 32)];
        float kp = (float)qkv[base + 768 + h * 64 + (d ^ 32)];
        int jj = d & 31;
        float invf = __expf(-(float)jj * (9.210340371976184f / 32.f)); // 10000^(-j/32)
        float ang = (float)sg * invf;
        float cv, sv;
        __sincosf(ang, &sv, &cv);
        float rq = (d < 32) ? -qp : qp;
        float rk = (d < 32) ? -kp : kp;
        qb[((size_t)bh * 2048 + sg) * 64 + d] = (bf16)((qv * cv + rq * sv) * qscale);
        kb[((size_t)bh * 2048 + sg) * 64 + d] = (bf16)(kv * cv + rk * sv);
        vs[sl][d] = vv;
    }
    __syncthreads();
#pragma unroll
    for (int i = 0; i < 16; ++i) {
        int idx = i * 256 + tid;
        int d = idx >> 6, sl = idx & 63;
        vtb[(size_t)bh * 64 * 2048 + (size_t)d * 2048 + s0 + sl] = (bf16)vs[sl][d];
    }
}

// ---------------------------------------------------------------- flash attention (causal)
// 768 blocks, XCD-swizzled: each XCD owns 3 heads (KV ~1.5MB resident in its L2),
// largest-qt-first within the XCD's stream.
__global__ __launch_bounds__(256) void attn_kernel(const bf16* __restrict__ qb,
                                                   const bf16* __restrict__ kb,
                                                   const bf16* __restrict__ vtb,
                                                   bf16* __restrict__ ob) {
    __shared__ __align__(16) bf16 Qs[2][64][32];        // 8 KB (staging only)
    __shared__ __align__(16) bf16 Ks[2][2][64][32];     // 16 KB: [tile][kk][kv][d]
    __shared__ __align__(16) bf16 Vts[2][2][64][32];    // 16 KB: [tile][kk][d][kv]
    __shared__ __align__(16) bf16 Ps[4][1024];          // 8 KB: per-wave P, chunk-swizzled

    const int tid = threadIdx.x, lane = tid & 63, w = tid >> 6;
    const int quad = lane >> 4, l16 = lane & 15;
    const int linear = (int)blockIdx.y * 32 + (int)blockIdx.x;
    const int xcd = linear & 7, j = linear >> 3;
    const int bh = xcd * 3 + (j >> 5);
    const int qt = 31 - (j & 31);                       // largest-first within XCD
    const int q0 = qt * 64;
    const int b = bh / 12, h = bh - b * 12;

    const bf16* qhead = qb + (size_t)bh * 2048 * 64;
    const bf16* khead = kb + (size_t)bh * 2048 * 64;
    const bf16* vthead = vtb + (size_t)bh * 64 * 2048;

#pragma unroll
    for (int i = 0; i < 2; ++i) {
        int o = (i * 256 + tid) * 16;
        int kk = o >> 12, row = (o >> 6) & 63, el = (o & 63) >> 1;
        async_cp16(qhead + (size_t)(q0 + row) * 64 + kk * 32 + el,
                   (char*)Qs + (size_t)(i * 256 + w * 64) * 16);
    }
    __syncthreads();
    bf16x8 bq[2];
#pragma unroll
    for (int kk = 0; kk < 2; ++kk)
        bq[kk] = *(const bf16x8*)&Qs[kk][w * 16 + l16][quad * 8];

    f32x4 o_acc[4] = {};
    float m_st = -1e30f, l_st = 0.f;

    for (int j2 = 0; j2 <= qt; j2 += 2) {
        int nt2 = (j2 + 1 <= qt) ? 2 : 1;
        __syncthreads();
#pragma unroll
        for (int t = 0; t < 2; ++t) {
            if (t >= nt2) break;
            int kv0 = (j2 + t) * 64;
#pragma unroll
            for (int i = 0; i < 2; ++i) {
                int o = (i * 256 + tid) * 16;
                int kk = o >> 12, row = (o >> 6) & 63, el = (o & 63) >> 1;
                async_cp16(khead + (size_t)(kv0 + row) * 64 + kk * 32 + el,
                           (char*)&Ks[t] + (size_t)(i * 256 + w * 64) * 16);
                async_cp16(vthead + (size_t)row * 2048 + kv0 + kk * 32 + el,
                           (char*)&Vts[t] + (size_t)(i * 256 + w * 64) * 16);
            }
        }
        __syncthreads();

#pragma unroll
        for (int t = 0; t < 2; ++t) {
            if (t >= nt2) break;

            f32x4 sacc[4] = {};
#pragma unroll
            for (int kk = 0; kk < 2; ++kk) {
                bf16x8 ak[4];
#pragma unroll
                for (int ni = 0; ni < 4; ++ni)
                    ak[ni] = *(const bf16x8*)&Ks[t][kk][ni * 16 + l16][quad * 8];
#pragma unroll
                for (int ni = 0; ni < 4; ++ni)
                    sacc[ni] = __builtin_amdgcn_mfma_f32_16x16x32_bf16(ak[ni], bq[kk], sacc[ni], 0, 0, 0);
            }

            if (j2 + t == qt) {
                int ql = w * 16 + l16;
#pragma unroll
                for (int ni = 0; ni < 4; ++ni)
#pragma unroll
                    for (int r = 0; r < 4; ++r)
                        if (ni * 16 + quad * 4 + r > ql) sacc[ni][r] = -1e30f;
            }

            float mx = sacc[0][0];
#pragma unroll
            for (int ni = 0; ni < 4; ++ni)
#pragma unroll
                for (int r = 0; r < 4; ++r) mx = fmaxf(mx, sacc[ni][r]);
            mx = fmaxf(mx, __shfl_xor(mx, 16, 64));
            mx = fmaxf(mx, __shfl_xor(mx, 32, 64));
            float mnew = fmaxf(m_st, mx);
            float alpha = exp2f(m_st - mnew);
            m_st = mnew;
            float rsum = 0.f;
#pragma unroll
            for (int ni = 0; ni < 4; ++ni)
#pragma unroll
                for (int r = 0; r < 4; ++r) {
                    float pv = exp2f(sacc[ni][r] - mnew);
                    sacc[ni][r] = pv;
                    rsum += pv;
                }
            rsum += __shfl_xor(rsum, 16, 64);
            rsum += __shfl_xor(rsum, 32, 64);
            l_st = l_st * alpha + rsum;

            float af[4];
#pragma unroll
            for (int r = 0; r < 4; ++r) af[r] = __shfl(alpha, quad * 4 + r, 64);
#pragma unroll
            for (int ni = 0; ni < 4; ++ni)
#pragma unroll
                for (int r = 0; r < 4; ++r) o_acc[ni][r] *= af[r];

            bf16* pb = Ps[w];
#pragma unroll
            for (int ni = 0; ni < 4; ++ni)
#pragma unroll
                for (int r = 0; r < 4; ++r) {
                    int kv = ni * 16 + quad * 4 + r;
                    int ch = (kv >> 3) ^ (l16 & 7);
                    pb[l16 * 64 + ch * 8 + (kv & 7)] = (bf16)sacc[ni][r];
                }

#pragma unroll
            for (int kk = 0; kk < 2; ++kk) {
                int ch = (kk * 4 + quad) ^ (l16 & 7);
                bf16x8 ap = *(const bf16x8*)&pb[l16 * 64 + ch * 8];
                bf16x8 bv[4];
#pragma unroll
                for (int ni = 0; ni < 4; ++ni)
                    bv[ni] = *(const bf16x8*)&Vts[t][kk][ni * 16 + l16][quad * 8];
#pragma unroll
                for (int ni = 0; ni < 4; ++ni)
                    o_acc[ni] = __builtin_amdgcn_mfma_f32_16x16x32_bf16(ap, bv[ni], o_acc[ni], 0, 0, 0);
            }
        }
    }

    float lf[4];
#pragma unroll
    for (int r = 0; r < 4; ++r) lf[r] = 1.f / __shfl(l_st, quad * 4 + r, 64);
#pragma unroll
    for (int ni = 0; ni < 4; ++ni)
#pragma unroll
        for (int r = 0; r < 4; ++r) {
            int rowg = q0 + w * 16 + quad * 4 + r;
            size_t tk = (size_t)b * 2048 + rowg;
            ob[tk * 768 + h * 64 + ni * 16 + l16] = (bf16)(o_acc[ni][r] * lf[r]);
        }
}

// ---------------------------------------------------------------- fused rmsnorm2 + router (NO atomics)
__global__ __launch_bounds__(256) void rms_router(const float* __restrict__ x1,
                                                  const float* __restrict__ w,
                                                  const float* __restrict__ rw,
                                                  bf16* __restrict__ hn,
                                                  int* __restrict__ topi,
                                                  float* __restrict__ topw,
                                                  float* __restrict__ probsb) {
    __shared__ float hnf[768];
    __shared__ float part[256];
    __shared__ float lg[8];
    __shared__ float probs[8];
    __shared__ float red[4];
    int row = blockIdx.x, tid = threadIdx.x;
    const float* xr = x1 + (size_t)row * 768;
    float v0 = xr[tid], v1 = xr[tid + 256], v2 = xr[tid + 512];
    float s = v0 * v0 + v1 * v1 + v2 * v2;
#pragma unroll
    for (int off = 32; off; off >>= 1) s += __shfl_xor(s, off, 64);
    if ((tid & 63) == 0) red[tid >> 6] = s;
    __syncthreads();
    float tot = red[0] + red[1] + red[2] + red[3];
    float rs = rsqrtf(tot * (1.f / 768.f) + 1e-6f);
    float h0 = v0 * rs * w[tid], h1v = v1 * rs * w[tid + 256], h2v = v2 * rs * w[tid + 512];
    hnf[tid] = h0; hnf[tid + 256] = h1v; hnf[tid + 512] = h2v;
    bf16* o = hn + (size_t)row * 768;
    o[tid] = (bf16)h0; o[tid + 256] = (bf16)h1v; o[tid + 512] = (bf16)h2v;
    __syncthreads();
    int e = tid & 7, seg = tid >> 3;
    float p = 0.f;
#pragma unroll
    for (int j = 0; j < 24; ++j) { int k = seg * 24 + j; p += hnf[k] * rw[k * 8 + e]; }
    part[tid] = p;
    __syncthreads();
    if (tid < 8) { float a = 0.f; for (int sgi = 0; sgi < 32; ++sgi) a += part[sgi * 8 + tid]; lg[tid] = a; }
    __syncthreads();
    if (tid == 0) {
        float mx = lg[0];
        for (int i = 1; i < 8; ++i) mx = fmaxf(mx, lg[i]);
        float ssum = 0.f, ex[8];
        for (int i = 0; i < 8; ++i) { ex[i] = __expf(lg[i] - mx); ssum += ex[i]; }
        float inv = 1.f / ssum;
        for (int i = 0; i < 8; ++i) probs[i] = ex[i] * inv;
        int e0 = 0; float p0 = probs[0];
        for (int i = 1; i < 8; ++i) if (probs[i] > p0) { p0 = probs[i]; e0 = i; }
        int e1 = -1; float p1 = -1.f;
        for (int i = 0; i < 8; ++i) if (i != e0 && probs[i] > p1) { p1 = probs[i]; e1 = i; }
        float wsum = p0 + p1;
        topi[row * 2] = e0; topi[row * 2 + 1] = e1;
        topw[row * 2] = p0 / wsum; topw[row * 2 + 1] = p1 / wsum;
    }
    __syncthreads();
    if (tid < 8) probsb[(size_t)row * 8 + tid] = probs[tid];
}

// ---------------------------------------------------------------- router stats + tiles + aux (single block)
__global__ __launch_bounds__(256) void router_stats(const float* __restrict__ probsb,
                                                    const int* __restrict__ topi,
                                                    int* ctrl, int4* tiles, float* auxOut) {
    __shared__ float pws[4][8];
    __shared__ int cws[4][8];
    int tid = threadIdx.x;
    float s[8] = {};
    int cnt[8] = {};
    for (int t = tid; t < 4096; t += 256) {
        const float4* p = (const float4*)(probsb + (size_t)t * 8);
        float4 a = p[0], b = p[1];
        s[0] += a.x; s[1] += a.y; s[2] += a.z; s[3] += a.w;
        s[4] += b.x; s[5] += b.y; s[6] += b.z; s[7] += b.w;
        int e0 = topi[2 * t], e1 = topi[2 * t + 1];
#pragma unroll
        for (int e = 0; e < 8; ++e) cnt[e] += (e == e0) + (e == e1);
    }
#pragma unroll
    for (int e = 0; e < 8; ++e)
#pragma unroll
        for (int off = 32; off; off >>= 1) {
            s[e] += __shfl_xor(s[e], off, 64);
            cnt[e] += __shfl_xor(cnt[e], off, 64);
        }
    if ((tid & 63) == 0) {
#pragma unroll
        for (int e = 0; e < 8; ++e) { pws[tid >> 6][e] = s[e]; cws[tid >> 6][e] = cnt[e]; }
    }
    __syncthreads();
    if (tid == 0) {
        int off = 0, nt = 0;
        float aux = 0.f;
        for (int e = 0; e < 8; ++e) {
            int ne = cws[0][e] + cws[1][e] + cws[2][e] + cws[3][e];
            float ps = pws[0][e] + pws[1][e] + pws[2][e] + pws[3][e];
            ctrl[e] = ne;
            ctrl[32 + e] = off;
            int ntl = (ne + 127) >> 7;
            for (int i = 0; i < ntl; ++i) { tiles[nt] = make_int4(e, off + i * 128, off + ne, 0); ++nt; }
            off += ntl << 7;
            aux += ((float)ne * (1.f / 8192.f)) * (ps * (1.f / 4096.f));
        }
        ctrl[24] = nt;
        auxOut[0] = 8.f * aux;
    }
}

// ---------------------------------------------------------------- token placement (hierarchical, few atomics)
__global__ __launch_bounds__(256) void place_tokens(const int* __restrict__ topi,
                                                    int* ctrl, int* __restrict__ perm,
                                                    int* __restrict__ tokslot) {
    __shared__ int lcnt[8], lbase[8];
    int tid = threadIdx.x;
    int t = blockIdx.x * 256 + tid;
    if (tid < 8) lcnt[tid] = 0;
    __syncthreads();
    int e0 = topi[2 * t], e1 = topi[2 * t + 1];
    int p0 = atomicAdd(&lcnt[e0], 1);
    int p1 = atomicAdd(&lcnt[e1], 1);
    __syncthreads();
    if (tid < 8) lbase[tid] = atomicAdd(&ctrl[16 + tid], lcnt[tid]);
    __syncthreads();
    int g0 = ctrl[32 + e0] + lbase[e0] + p0;
    int g1 = ctrl[32 + e1] + lbase[e1] + p1;
    perm[g0] = t; perm[g1] = t;
    tokslot[2 * t] = g0; tokslot[2 * t + 1] = g1;
}

// ---------------------------------------------------------------- final combine: out += w0*h2[s0] + w1*h2[s1]
__global__ __launch_bounds__(256) void moe_combine(const bf16* __restrict__ h2,
                                                   const int* __restrict__ tokslot,
                                                   const float* __restrict__ topw,
                                                   float* __restrict__ out) {
    int t = blockIdx.x, tid = threadIdx.x;
    int s0 = tokslot[2 * t], s1 = tokslot[2 * t + 1];
    float w0 = topw[2 * t], w1 = topw[2 * t + 1];
    const bf16* r0 = h2 + (size_t)s0 * 768;
    const bf16* r1 = h2 + (size_t)s1 * 768;
    float* o = out + (size_t)t * 768;
#pragma unroll
    for (int i = 0; i < 3; ++i) {
        int c = i * 256 + tid;
        o[c] += w0 * (float)r0[c] + w1 * (float)r1[c];
    }
}

// ---------------------------------------------------------------- NT GEMM: C[M,N] = A[M,K] @ Bt[N,K]^T
// 1D grid with XCD-locality swizzle: xcd = L&7 owns MTX consecutive m-tiles;
// all NBX n-blocks of a tile run on that XCD -> A-tile fetched once per chip.
// Double-buffered LDS K-loop (one barrier/round).
// MODE 0: out bf16 (qkv)   MODE 1: out fp32 + residual (wo)
// MODE 2: gathered rows (perm) + silu -> bf16 (moe h1)
// MODE 3: direct rows -> bf16 h2 slot rows
template <int MODE, int NBX, int MTX>
__global__ __launch_bounds__(256) void gemm_nt(const bf16* __restrict__ A,
                                               const bf16* __restrict__ Bt,
                                               int N, int K,
                                               const float* __restrict__ xres,
                                               float* __restrict__ outF,
                                               bf16* __restrict__ outB,
                                               const int4* __restrict__ tiles,
                                               const int* __restrict__ ctrl,
                                               const int* __restrict__ perm) {
    __shared__ __align__(16) bf16 As[2][128 * 32];
    __shared__ __align__(16) bf16 Bs[2][128 * 32];
    __shared__ int sPerm[128];

    const int tid = threadIdx.x, lane = tid & 63, w = tid >> 6;
    const int wr = w >> 1, wc = w & 1, quad = lane >> 4, l16 = lane & 15;

    const int L = blockIdx.x;
    const int xcd = L & 7, j = L >> 3;
    const int mt = xcd * MTX + j / NBX;
    const int n0 = (j % NBX) * 128;

    int m0 = 0, row0 = 0;
    if (MODE <= 1) {
        m0 = mt * 128;
    } else {
        if (mt >= ctrl[24]) return;
        int4 td = tiles[mt];
        row0 = td.y;
        int rowend = td.z;
        Bt += (size_t)td.x * N * K;
        if (MODE == 2 && tid < 128) {
            int g = row0 + tid;
            int gs = (g < rowend) ? g : row0;   // clamp padded rows to a valid one
            sPerm[tid] = perm[gs];
        }
        if (MODE == 2) __syncthreads();          // sPerm visible before first staging
    }

    auto stage = [&](int buf, int kt) {
#pragma unroll
        for (int i = 0; i < 2; ++i) {
            int c = i * 256 + tid;
            int r = c >> 2, koff = (c & 3) * 8;
            const bf16* gp;
            if (MODE == 2)      gp = A + (size_t)sPerm[r] * K + kt + koff;
            else if (MODE == 3) gp = A + (size_t)(row0 + r) * K + kt + koff;
            else                gp = A + (size_t)(m0 + r) * K + kt + koff;
            async_cp16(gp, (char*)As[buf] + (size_t)(i * 256 + w * 64) * 16);
            async_cp16(Bt + (size_t)(n0 + r) * K + kt + koff,
                       (char*)Bs[buf] + (size_t)(i * 256 + w * 64) * 16);
        }
    };

    f32x4 acc[4][4] = {};
    const int nIt = K >> 5;
    stage(0, 0);

    for (int it = 0; it < nIt; ++it) {
        const int cur = it & 1;
        __syncthreads();                         // cur staged; prev reads of cur^1 done
        if (it + 1 < nIt) stage(cur ^ 1, (it + 1) << 5);

        bf16x8 af[4], bfr[4];
#pragma unroll
        for (int mi = 0; mi < 4; ++mi)
            af[mi] = *(const bf16x8*)(As[cur] + (wr * 64 + mi * 16 + l16) * 32 + quad * 8);
#pragma unroll
        for (int ni = 0; ni < 4; ++ni)
            bfr[ni] = *(const bf16x8*)(Bs[cur] + (wc * 64 + ni * 16 + l16) * 32 + quad * 8);
#pragma unroll
        for (int mi = 0; mi < 4; ++mi)
#pragma unroll
            for (int ni = 0; ni < 4; ++ni)
                acc[mi][ni] = __builtin_amdgcn_mfma_f32_16x16x32_bf16(af[mi], bfr[ni], acc[mi][ni], 0, 0, 0);
    }

#pragma unroll
    for (int mi = 0; mi < 4; ++mi)
#pragma unroll
        for (int ni = 0; ni < 4; ++ni)
#pragma unroll
            for (int r = 0; r < 4; ++r) {
                int lrow = wr * 64 + mi * 16 + quad * 4 + r;
                int col = n0 + wc * 64 + ni * 16 + l16;
                float v = acc[mi][ni][r];
                if (MODE == 0) {
                    outB[(size_t)(m0 + lrow) * N + col] = (bf16)v;
                } else if (MODE == 1) {
                    size_t idx = (size_t)(m0 + lrow) * N + col;
                    outF[idx] = v + xres[idx];
                } else if (MODE == 2) {
                    float sv = v / (1.f + __expf(-v));   // silu
                    outB[(size_t)(row0 + lrow) * N + col] = (bf16)sv;
                } else {
                    outB[(size_t)(row0 + lrow) * N + col] = (bf16)v;   // h2 slot row
                }
            }
}

__global__ void zero_ctrl(int* ctrl) { if (threadIdx.x < 64) ctrl[threadIdx.x] = 0; }

// ---------------------------------------------------------------- launch
extern "C" void kernel_launch(void* const* d_in, const int* in_sizes, int n_in,
                              void* d_out, int out_size, void* d_ws, size_t ws_size,
                              hipStream_t stream) {
    const float* x    = (const float*)d_in[0];
    const float* anw  = (const float*)d_in[1];
    const float* wqkv = (const float*)d_in[2];
    const float* wo   = (const float*)d_in[3];
    const float* fnw  = (const float*)d_in[4];
    const float* rw   = (const float*)d_in[5];
    const float* w1   = (const float*)d_in[6];
    const float* w2   = (const float*)d_in[7];
    float* out = (float*)d_out;

    char* ws = (char*)d_ws;
    size_t off = 0;
    auto alloc = [&](size_t bytes) -> char* {
        char* p = ws + off;
        off = (off + bytes + 255) & ~(size_t)255;
        return p;
    };
    bf16* wqkvT = (bf16*)alloc(2304ull * 768 * 2);
    bf16* woT   = (bf16*)alloc(768ull * 768 * 2);
    bf16* w1T   = (bf16*)alloc(8ull * 3072 * 768 * 2);
    bf16* w2T   = (bf16*)alloc(8ull * 768 * 3072 * 2);
    bf16* hbuf  = (bf16*)alloc(4096ull * 768 * 2);
    bf16* qkvb  = (bf16*)alloc(4096ull * 2304 * 2);   // reused as h2 slot buffer in MoE phase
    bf16* qb    = (bf16*)alloc(24ull * 2048 * 64 * 2);
    bf16* kb    = (bf16*)alloc(24ull * 2048 * 64 * 2);
    bf16* vtb   = (bf16*)alloc(24ull * 64 * 2048 * 2);
    bf16* obuf  = (bf16*)alloc(4096ull * 768 * 2);
    bf16* hn    = (bf16*)alloc(4096ull * 768 * 2);
    int*  topi  = (int*)alloc(4096ull * 2 * 4);
    float* topw = (float*)alloc(4096ull * 2 * 4);
    float* probsb = (float*)alloc(4096ull * 8 * 4);
    int*  ctrl  = (int*)alloc(64 * 4);
    int4* tiles = (int4*)alloc(80 * 16);
    int*  perm  = (int*)alloc(9216 * 4);
    int*  tokslot = (int*)alloc(4096ull * 2 * 4);
    bf16* h1    = (bf16*)alloc(9216ull * 3072 * 2);
    bf16* h2    = qkvb;                                // alias: qkvb dead after rope
    (void)ws_size; (void)in_sizes; (void)n_in;

    zero_ctrl<<<1, 64, 0, stream>>>(ctrl);
    // weight transpose+casts to bf16 [N][K]
    transpose_cast<<<dim3(72, 24, 1), 256, 0, stream>>>(wqkv, wqkvT, 768, 2304);
    transpose_cast<<<dim3(24, 24, 1), 256, 0, stream>>>(wo, woT, 768, 768);
    transpose_cast<<<dim3(96, 24, 8), 256, 0, stream>>>(w1, w1T, 768, 3072);
    transpose_cast<<<dim3(24, 96, 8), 256, 0, stream>>>(w2, w2T, 3072, 768);
    // attention block
    rmsnorm_cast<<<4096, 256, 0, stream>>>(x, anw, hbuf);
    gemm_nt<0, 18, 4><<<576, 256, 0, stream>>>(hbuf, wqkvT, 2304, 768,
                                               nullptr, nullptr, qkvb, nullptr, nullptr, nullptr);
    rope_kernel<<<dim3(32, 24), 256, 0, stream>>>(qkvb, qb, kb, vtb);
    attn_kernel<<<dim3(32, 24), 256, 0, stream>>>(qb, kb, vtb, obuf);
    gemm_nt<1, 6, 4><<<192, 256, 0, stream>>>(obuf, woT, 768, 768,
                                              x, out, nullptr, nullptr, nullptr, nullptr);
    // MoE block
    rms_router<<<4096, 256, 0, stream>>>(out, fnw, rw, hn, topi, topw, probsb);
    router_stats<<<1, 256, 0, stream>>>(probsb, topi, ctrl, tiles, out + (out_size - 1));
    place_tokens<<<16, 256, 0, stream>>>(topi, ctrl, perm, tokslot);
    gemm_nt<2, 24, 9><<<1728, 256, 0, stream>>>(hn, w1T, 3072, 768,
                                                nullptr, nullptr, h1, tiles, ctrl, perm);
    gemm_nt<3, 6, 9><<<432, 256, 0, stream>>>(h1, w2T, 768, 3072,
                                              nullptr, nullptr, h2, tiles, ctrl, perm);
    moe_combine<<<4096, 256, 0, stream>>>(h2, tokslot, topw, out);
}